// Round 3
// baseline (163.728 us; speedup 1.0000x reference)
//
#include <hip/hip_runtime.h>

typedef unsigned short u16;
typedef unsigned int u32;

#define B_   4
#define C_   256
#define CI_  128
#define H_   64
#define W_   64
#define NPB_ 4096     // pixels per batch image
#define NP_  16384    // total pixels
#define K_   9        // 3x3 taps

__device__ __forceinline__ float bf2f(u16 u) {
    union { u32 i; float f; } x; x.i = ((u32)u) << 16; return x.f;
}
__device__ __forceinline__ float bf2f_lo(u32 w) {
    union { u32 i; float f; } x; x.i = w << 16; return x.f;
}
__device__ __forceinline__ float bf2f_hi(u32 w) {
    union { u32 i; float f; } x; x.i = w & 0xffff0000u; return x.f;
}
__device__ __forceinline__ u16 f2bf(float f) {  // round-to-nearest-even
    union { float f; u32 i; } x; x.f = f;
    u32 lsb = (x.i >> 16) & 1u;
    return (u16)((x.i + 0x7fffu + lsb) >> 16);
}

// k0: wcomb[c] = sum_o Wo[o]*Wv[o][c]; vsb = Wo·bv
__global__ void k0_combine(const float* __restrict__ Wv, const float* __restrict__ Wo,
                           const float* __restrict__ bv, float* __restrict__ wcomb,
                           float* __restrict__ vsb) {
    const int c = threadIdx.x;
    float s = 0.f;
    for (int o = 0; o < CI_; ++o)
        s += Wo[o] * Wv[o * C_ + c];
    wcomb[c] = s;
    if (c == 0) {
        float tsum = 0.f;
        for (int o = 0; o < CI_; ++o) tsum += Wo[o] * bv[o];
        *vsb = tsum;
    }
}

// k1: per pixel p: qk[p][0..127]=q, qk[p][128..255]=k (bf16, channel-last);
//     vs[p] = x[:,p]·wcomb + vsb  (f32)
__global__ __launch_bounds__(256) void k1_proj(
    const float* __restrict__ x,
    const float* __restrict__ Wq, const float* __restrict__ bq,
    const float* __restrict__ Wk, const float* __restrict__ bk,
    const float* __restrict__ wcomb, const float* __restrict__ vsb,
    u16* __restrict__ qk, float* __restrict__ vs) {
    __shared__ u16 xs[C_][68];      // [c][px], padded (8B-aligned rows)
    __shared__ u16 ws[64][264];     // transposed W chunk: [cj][o], 16B-aligned rows
    __shared__ float vscr[4][64];
    const int t   = threadIdx.x;
    const int p0  = blockIdx.x * 64;
    const int b   = p0 >> 12;
    const int pin = p0 & 4095;

    {   // stage x tile [256 c][64 px], coalesced over px
        const int px = t & 63, c4 = t >> 6;
        #pragma unroll 4
        for (int r = 0; r < 64; ++r) {
            const int c = r * 4 + c4;
            xs[c][px] = f2bf(x[(size_t)(b * C_ + c) * NPB_ + pin + px]);
        }
    }

    const int px0 = (t & 15) * 4;   // 4 pixels per thread
    const int og  = t >> 4;         // 16 outputs per thread
    float acc[4][16];
    #pragma unroll
    for (int k = 0; k < 16; ++k) {
        const int o = og * 16 + k;
        const float bias = (o < CI_) ? bq[o] : bk[o - CI_];
        acc[0][k] = bias; acc[1][k] = bias; acc[2][k] = bias; acc[3][k] = bias;
    }

    for (int cb = 0; cb < 4; ++cb) {
        const int cbase = cb * 64;
        if (cb) __syncthreads();     // previous chunk's readers done before re-stage
        {   // stage W chunk transposed: ws[cj][o] = W[o][cbase+cj]
            const int cj = t & 63, o4 = t >> 6;
            #pragma unroll 4
            for (int r = 0; r < 64; ++r) {
                const int o = r * 4 + o4;
                ws[cj][o] = f2bf((o < CI_) ? Wq[o * C_ + cbase + cj]
                                           : Wk[(o - CI_) * C_ + cbase + cj]);
            }
        }
        __syncthreads();
        #pragma unroll 2
        for (int cj = 0; cj < 64; ++cj) {
            const ushort4 xr = *reinterpret_cast<const ushort4*>(&xs[cbase + cj][px0]);
            float xv[4];
            xv[0] = bf2f(xr.x); xv[1] = bf2f(xr.y); xv[2] = bf2f(xr.z); xv[3] = bf2f(xr.w);
            const uint4 w0 = *reinterpret_cast<const uint4*>(&ws[cj][og * 16]);
            const uint4 w1 = *reinterpret_cast<const uint4*>(&ws[cj][og * 16 + 8]);
            float wv[16];
            wv[0]=bf2f_lo(w0.x); wv[1]=bf2f_hi(w0.x); wv[2]=bf2f_lo(w0.y); wv[3]=bf2f_hi(w0.y);
            wv[4]=bf2f_lo(w0.z); wv[5]=bf2f_hi(w0.z); wv[6]=bf2f_lo(w0.w); wv[7]=bf2f_hi(w0.w);
            wv[8]=bf2f_lo(w1.x); wv[9]=bf2f_hi(w1.x); wv[10]=bf2f_lo(w1.y); wv[11]=bf2f_hi(w1.y);
            wv[12]=bf2f_lo(w1.z); wv[13]=bf2f_hi(w1.z); wv[14]=bf2f_lo(w1.w); wv[15]=bf2f_hi(w1.w);
            #pragma unroll
            for (int i = 0; i < 4; ++i)
                #pragma unroll
                for (int k = 0; k < 16; ++k)
                    acc[i][k] += xv[i] * wv[k];
        }
    }

    {   // vs partial sums (xs is read-only since first sync)
        const int px = t & 63, qg = t >> 6;   // qg is wave-uniform
        float s = 0.f;
        #pragma unroll 4
        for (int cc = 0; cc < 64; ++cc) {
            const int c = qg * 64 + cc;
            s += bf2f(xs[c][px]) * wcomb[c];
        }
        vscr[qg][px] = s;
    }

    // qk writeback: 2x uint4 (16B) stores per pixel-row
    #pragma unroll
    for (int i = 0; i < 4; ++i) {
        u32 pr[8];
        #pragma unroll
        for (int k = 0; k < 8; ++k)
            pr[k] = (u32)f2bf(acc[i][2 * k]) | ((u32)f2bf(acc[i][2 * k + 1]) << 16);
        uint4 va, vb;
        va.x = pr[0]; va.y = pr[1]; va.z = pr[2]; va.w = pr[3];
        vb.x = pr[4]; vb.y = pr[5]; vb.z = pr[6]; vb.w = pr[7];
        uint4* dst = reinterpret_cast<uint4*>(qk + (size_t)(p0 + px0 + i) * C_ + og * 16);
        dst[0] = va; dst[1] = vb;
    }

    __syncthreads();
    if (t < 64) {
        const float s = vscr[0][t] + vscr[1][t] + vscr[2][t] + vscr[3][t] + *vsb;
        vs[p0 + t] = s;
    }
}

// k2: one wave per pixel. lane = channel pair (2l, 2l+1).
__global__ __launch_bounds__(256) void k2_attn(
    const float* __restrict__ off, const u16* __restrict__ qk,
    const float* __restrict__ vs, const float* __restrict__ bo,
    float* __restrict__ out) {
    const int t = threadIdx.x;
    const int l = t & 63;
    const int pixel = blockIdx.x * 4 + (t >> 6);
    const int b = pixel >> 12;
    const int rem = pixel & 4095;
    const int y = rem >> 6, xx = rem & 63;

    float qu0[K_], qu1[K_], ku0[K_], ku1[K_], vsu[K_];
    #pragma unroll
    for (int i = 0; i < K_; ++i) { qu0[i]=0.f; qu1[i]=0.f; ku0[i]=0.f; ku1[i]=0.f; vsu[i]=0.f; }

    const float* offb = off + (size_t)b * 2 * K_ * NPB_ + rem;
    const u16* qkb    = qk + (size_t)(b << 12) * C_;
    const float* vsm  = vs + (b << 12);

    #pragma unroll
    for (int tap = 0; tap < K_; ++tap) {
        const float oy = offb[(size_t)(2 * tap) * NPB_];
        const float ox = offb[(size_t)(2 * tap + 1) * NPB_];
        const float py = (float)(y + (tap / 3) - 1) + oy;
        const float px = (float)(xx + (tap % 3) - 1) + ox;
        const float fy0 = floorf(py), fx0 = floorf(px);
        const float fy = py - fy0, fx = px - fx0;
        const int y0 = (int)fy0, x0 = (int)fx0;
        #pragma unroll
        for (int dy = 0; dy < 2; ++dy) {
            const int yi = y0 + dy;
            if (yi < 0 || yi >= H_) continue;       // zero padding
            const float wy = dy ? fy : 1.f - fy;
            #pragma unroll
            for (int dx = 0; dx < 2; ++dx) {
                const int xi = x0 + dx;
                if (xi < 0 || xi >= W_) continue;
                const float w = wy * (dx ? fx : 1.f - fx);
                const int pp = yi * W_ + xi;
                const u16* base = qkb + (size_t)pp * C_;
                const u32 qv = *reinterpret_cast<const u32*>(base + 2 * l);
                const u32 kv = *reinterpret_cast<const u32*>(base + CI_ + 2 * l);
                qu0[tap] += w * bf2f_lo(qv);
                qu1[tap] += w * bf2f_hi(qv);
                ku0[tap] += w * bf2f_lo(kv);
                ku1[tap] += w * bf2f_hi(kv);
                vsu[tap] += w * vsm[pp];            // lane-uniform
            }
        }
    }

    const float bof = bo[0];
    const size_t obase = (size_t)b * K_ * NPB_ + rem;
    #pragma unroll
    for (int i = 0; i < K_; ++i) {
        float r[K_];
        #pragma unroll
        for (int j = 0; j < K_; ++j)
            r[j] = qu0[i] * ku0[j] + qu1[i] * ku1[j];   // partial over this lane's 2 ch
        #pragma unroll
        for (int st = 1; st < 64; st <<= 1) {           // 64-lane butterfly sum
            #pragma unroll
            for (int j = 0; j < K_; ++j)
                r[j] += __shfl_xor(r[j], st, 64);
        }
        float m = r[0];
        #pragma unroll
        for (int j = 1; j < K_; ++j) m = fmaxf(m, r[j]);
        float den = 0.f, num = 0.f;
        #pragma unroll
        for (int j = 0; j < K_; ++j) {
            const float e = __expf(r[j] - m);
            den += e;
            num += e * vsu[j];
        }
        if (l == 0) {
            const float z = num / den + bof;
            const float o = 1.f / (1.f + __expf(-z));
            out[obase + (size_t)i * NPB_] = o;
        }
    }
}

extern "C" void kernel_launch(void* const* d_in, const int* in_sizes, int n_in,
                              void* d_out, int out_size, void* d_ws, size_t ws_size,
                              hipStream_t stream) {
    const float* x   = (const float*)d_in[0];
    const float* off = (const float*)d_in[1];
    const float* Wq  = (const float*)d_in[2];
    const float* bq  = (const float*)d_in[3];
    const float* Wk  = (const float*)d_in[4];
    const float* bk  = (const float*)d_in[5];
    const float* Wv  = (const float*)d_in[6];
    const float* bv  = (const float*)d_in[7];
    const float* Wo  = (const float*)d_in[8];
    const float* bo  = (const float*)d_in[9];
    float* out = (float*)d_out;

    char* ws = (char*)d_ws;
    float* wcomb = (float*)ws;                                   // 256 f32
    float* vsb   = (float*)(ws + 1024);                          // 1 f32
    u16*   qkbuf = (u16*)(ws + 4096);                            // 16384*256 bf16 = 8 MiB
    float* vsmap = (float*)(ws + 4096 + (size_t)NP_ * C_ * 2);   // 16384 f32

    k0_combine<<<1, 256, 0, stream>>>(Wv, Wo, bv, wcomb, vsb);
    k1_proj<<<NP_ / 64, 256, 0, stream>>>(x, Wq, bq, Wk, bk, wcomb, vsb, qkbuf, vsmap);
    k2_attn<<<NP_ / 4, 256, 0, stream>>>(off, qkbuf, vsmap, bo, out);
}

// Round 4
// 116.311 us; speedup vs baseline: 1.4077x; 1.4077x over previous
//
#include <hip/hip_runtime.h>

typedef unsigned short u16;
typedef unsigned int u32;

#define B_   4
#define C_   256
#define CI_  128
#define H_   64
#define W_   64
#define NPB_ 4096     // pixels per batch image
#define NP_  16384    // total pixels
#define K_   9        // 3x3 taps

typedef __attribute__((ext_vector_type(8))) __bf16 bf16x8_t;
typedef __attribute__((ext_vector_type(4))) float f32x4_t;

__device__ __forceinline__ float bf2f(u16 u) {
    union { u32 i; float f; } x; x.i = ((u32)u) << 16; return x.f;
}
__device__ __forceinline__ float bf2f_lo(u32 w) {
    union { u32 i; float f; } x; x.i = w << 16; return x.f;
}
__device__ __forceinline__ float bf2f_hi(u32 w) {
    union { u32 i; float f; } x; x.i = w & 0xffff0000u; return x.f;
}
__device__ __forceinline__ u16 f2bf(float f) {  // round-to-nearest-even
    union { float f; u32 i; } x; x.f = f;
    u32 lsb = (x.i >> 16) & 1u;
    return (u16)((x.i + 0x7fffu + lsb) >> 16);
}
__device__ __forceinline__ void acc8(float* f, uint4 v, float w) {
    f[0] += w * bf2f_lo(v.x); f[1] += w * bf2f_hi(v.x);
    f[2] += w * bf2f_lo(v.y); f[3] += w * bf2f_hi(v.y);
    f[4] += w * bf2f_lo(v.z); f[5] += w * bf2f_hi(v.z);
    f[6] += w * bf2f_lo(v.w); f[7] += w * bf2f_hi(v.w);
}

// k0: wcomb[c] = sum_o Wo[o]*Wv[o][c]; vsb = Wo·bv
__global__ void k0_combine(const float* __restrict__ Wv, const float* __restrict__ Wo,
                           const float* __restrict__ bv, float* __restrict__ wcomb,
                           float* __restrict__ vsb) {
    const int c = threadIdx.x;
    float s = 0.f;
    for (int o = 0; o < CI_; ++o)
        s += Wo[o] * Wv[o * C_ + c];
    wcomb[c] = s;
    if (c == 0) {
        float tsum = 0.f;
        for (int o = 0; o < CI_; ++o) tsum += Wo[o] * bv[o];
        *vsb = tsum;
    }
}

// k1: per pixel p: qk[p][0..127]=q, qk[p][128..255]=k (bf16, channel-last);
//     vs[p] = x[:,p]·wcomb + vsb  (f32)
__global__ __launch_bounds__(256) void k1_proj(
    const float* __restrict__ x,
    const float* __restrict__ Wq, const float* __restrict__ bq,
    const float* __restrict__ Wk, const float* __restrict__ bk,
    const float* __restrict__ wcomb, const float* __restrict__ vsb,
    u16* __restrict__ qk, float* __restrict__ vs) {
    __shared__ u16 xs[C_][68];      // [c][px], padded (8B-aligned rows)
    __shared__ u16 ws[64][264];     // transposed W chunk: [cj][o], 16B-aligned rows
    __shared__ float vscr[4][64];
    const int t   = threadIdx.x;
    const int p0  = blockIdx.x * 64;
    const int b   = p0 >> 12;
    const int pin = p0 & 4095;

    {   // stage x tile [256 c][64 px], coalesced over px
        const int px = t & 63, c4 = t >> 6;
        #pragma unroll 4
        for (int r = 0; r < 64; ++r) {
            const int c = r * 4 + c4;
            xs[c][px] = f2bf(x[(size_t)(b * C_ + c) * NPB_ + pin + px]);
        }
    }

    const int px0 = (t & 15) * 4;   // 4 pixels per thread
    const int og  = t >> 4;         // 16 outputs per thread
    float acc[4][16];
    #pragma unroll
    for (int k = 0; k < 16; ++k) {
        const int o = og * 16 + k;
        const float bias = (o < CI_) ? bq[o] : bk[o - CI_];
        acc[0][k] = bias; acc[1][k] = bias; acc[2][k] = bias; acc[3][k] = bias;
    }

    for (int cb = 0; cb < 4; ++cb) {
        const int cbase = cb * 64;
        if (cb) __syncthreads();     // previous chunk's readers done before re-stage
        {   // stage W chunk transposed: ws[cj][o] = W[o][cbase+cj]
            const int cj = t & 63, o4 = t >> 6;
            #pragma unroll 4
            for (int r = 0; r < 64; ++r) {
                const int o = r * 4 + o4;
                ws[cj][o] = f2bf((o < CI_) ? Wq[o * C_ + cbase + cj]
                                           : Wk[(o - CI_) * C_ + cbase + cj]);
            }
        }
        __syncthreads();
        #pragma unroll 2
        for (int cj = 0; cj < 64; ++cj) {
            const ushort4 xr = *reinterpret_cast<const ushort4*>(&xs[cbase + cj][px0]);
            float xv[4];
            xv[0] = bf2f(xr.x); xv[1] = bf2f(xr.y); xv[2] = bf2f(xr.z); xv[3] = bf2f(xr.w);
            const uint4 w0 = *reinterpret_cast<const uint4*>(&ws[cj][og * 16]);
            const uint4 w1 = *reinterpret_cast<const uint4*>(&ws[cj][og * 16 + 8]);
            float wv[16];
            wv[0]=bf2f_lo(w0.x); wv[1]=bf2f_hi(w0.x); wv[2]=bf2f_lo(w0.y); wv[3]=bf2f_hi(w0.y);
            wv[4]=bf2f_lo(w0.z); wv[5]=bf2f_hi(w0.z); wv[6]=bf2f_lo(w0.w); wv[7]=bf2f_hi(w0.w);
            wv[8]=bf2f_lo(w1.x); wv[9]=bf2f_hi(w1.x); wv[10]=bf2f_lo(w1.y); wv[11]=bf2f_hi(w1.y);
            wv[12]=bf2f_lo(w1.z); wv[13]=bf2f_hi(w1.z); wv[14]=bf2f_lo(w1.w); wv[15]=bf2f_hi(w1.w);
            #pragma unroll
            for (int i = 0; i < 4; ++i)
                #pragma unroll
                for (int k = 0; k < 16; ++k)
                    acc[i][k] += xv[i] * wv[k];
        }
    }

    {   // vs partial sums (xs is read-only since first sync)
        const int px = t & 63, qg = t >> 6;   // qg is wave-uniform
        float s = 0.f;
        #pragma unroll 4
        for (int cc = 0; cc < 64; ++cc) {
            const int c = qg * 64 + cc;
            s += bf2f(xs[c][px]) * wcomb[c];
        }
        vscr[qg][px] = s;
    }

    // qk writeback: 2x uint4 (16B) stores per pixel-row
    #pragma unroll
    for (int i = 0; i < 4; ++i) {
        u32 pr[8];
        #pragma unroll
        for (int k = 0; k < 8; ++k)
            pr[k] = (u32)f2bf(acc[i][2 * k]) | ((u32)f2bf(acc[i][2 * k + 1]) << 16);
        uint4 va, vb;
        va.x = pr[0]; va.y = pr[1]; va.z = pr[2]; va.w = pr[3];
        vb.x = pr[4]; vb.y = pr[5]; vb.z = pr[6]; vb.w = pr[7];
        uint4* dst = reinterpret_cast<uint4*>(qk + (size_t)(p0 + px0 + i) * C_ + og * 16);
        dst[0] = va; dst[1] = vb;
    }

    __syncthreads();
    if (t < 64) {
        const float s = vscr[0][t] + vscr[1][t] + vscr[2][t] + vscr[3][t] + *vsb;
        vs[p0 + t] = s;
    }
}

// k2: one wave per pixel. lane l: tap = l&15 (A-row j of ku AND B-col i of qu),
// channel slice c = step*32 + (l>>4)*8 + e. A/B share the (lane,elem)->k map, so
// any HW k-permutation cancels; C/D layout is the HW-verified col=l&15,
// row=(l>>4)*4+reg (m89). S = ku^T(.)qu via 4x mfma_f32_16x16x32_bf16.
__global__ __launch_bounds__(256) void k2_attn(
    const float* __restrict__ off, const u16* __restrict__ qk,
    const float* __restrict__ vs, const float* __restrict__ bo,
    float* __restrict__ out) {
    const int t = threadIdx.x;
    const int l = t & 63;
    const int pixel = blockIdx.x * 4 + (t >> 6);
    const int b = pixel >> 12;
    const int rem = pixel & 4095;
    const int y = rem >> 6, xx = rem & 63;
    const int tap = l & 15;
    const int g = l >> 4;

    float fq[32], fk[32];   // [s*8+e] bilinear-accumulated q/k channels (f32)
    #pragma unroll
    for (int e = 0; e < 32; ++e) { fq[e] = 0.f; fk[e] = 0.f; }
    float vsu_t = 0.f;

    if (tap < K_) {
        const float* offb = off + ((size_t)b * (2 * K_) + 2 * tap) * NPB_ + rem;
        const float oy = offb[0];
        const float ox = offb[NPB_];
        const float py = (float)(y + tap / 3 - 1) + oy;
        const float px = (float)(xx + tap % 3 - 1) + ox;
        const float fy0 = floorf(py), fx0 = floorf(px);
        const float fy = py - fy0, fx = px - fx0;
        const int y0 = (int)fy0, x0 = (int)fx0;
        const u16* qkb = qk + ((size_t)(b << 12)) * C_ + g * 8;
        const float* vsm = vs + (b << 12);
        #pragma unroll
        for (int dy = 0; dy < 2; ++dy) {
            const int yi = y0 + dy;
            if (yi < 0 || yi >= H_) continue;       // zero padding
            const float wy = dy ? fy : 1.f - fy;
            #pragma unroll
            for (int dx = 0; dx < 2; ++dx) {
                const int xi = x0 + dx;
                if (xi < 0 || xi >= W_) continue;
                const float w = wy * (dx ? fx : 1.f - fx);
                const int pp = yi * W_ + xi;
                const u16* base = qkb + (size_t)pp * C_;
                #pragma unroll
                for (int s = 0; s < 4; ++s) {
                    const uint4 qv = *reinterpret_cast<const uint4*>(base + s * 32);
                    const uint4 kv = *reinterpret_cast<const uint4*>(base + CI_ + s * 32);
                    acc8(&fq[s * 8], qv, w);
                    acc8(&fk[s * 8], kv, w);
                }
                vsu_t += w * vsm[pp];
            }
        }
    }

    // 4 MFMA steps: acc[r] = S[i = tap][j = g*4 + r]
    f32x4_t acc = {0.f, 0.f, 0.f, 0.f};
    #pragma unroll
    for (int s = 0; s < 4; ++s) {
        bf16x8_t av, bv;
        #pragma unroll
        for (int e = 0; e < 8; ++e) {
            av[e] = (__bf16)fk[s * 8 + e];   // A = ku (rows j)
            bv[e] = (__bf16)fq[s * 8 + e];   // B = qu (cols i)
        }
        acc = __builtin_amdgcn_mfma_f32_16x16x32_bf16(av, bv, acc, 0, 0, 0);
    }

    // softmax over j for fixed i = tap; j spread across lane groups (stride-16 lanes)
    float mx = -1e30f;
    #pragma unroll
    for (int r = 0; r < 4; ++r) {
        const int j = g * 4 + r;
        if (j < K_) mx = fmaxf(mx, acc[r]);
    }
    mx = fmaxf(mx, __shfl_xor(mx, 16, 64));
    mx = fmaxf(mx, __shfl_xor(mx, 32, 64));

    float vj[4];
    #pragma unroll
    for (int r = 0; r < 4; ++r) vj[r] = __shfl(vsu_t, g * 4 + r, 64);  // vsu[j] from lane j

    float den = 0.f, num = 0.f;
    #pragma unroll
    for (int r = 0; r < 4; ++r) {
        const int j = g * 4 + r;
        if (j < K_) {
            const float e = __expf(acc[r] - mx);
            den += e;
            num += e * vj[r];
        }
    }
    den += __shfl_xor(den, 16, 64); den += __shfl_xor(den, 32, 64);
    num += __shfl_xor(num, 16, 64); num += __shfl_xor(num, 32, 64);

    if (l < K_) {
        const float z = num / den + bo[0];
        out[(size_t)b * K_ * NPB_ + (size_t)l * NPB_ + rem] = 1.f / (1.f + __expf(-z));
    }
}

extern "C" void kernel_launch(void* const* d_in, const int* in_sizes, int n_in,
                              void* d_out, int out_size, void* d_ws, size_t ws_size,
                              hipStream_t stream) {
    const float* x   = (const float*)d_in[0];
    const float* off = (const float*)d_in[1];
    const float* Wq  = (const float*)d_in[2];
    const float* bq  = (const float*)d_in[3];
    const float* Wk  = (const float*)d_in[4];
    const float* bk  = (const float*)d_in[5];
    const float* Wv  = (const float*)d_in[6];
    const float* bv  = (const float*)d_in[7];
    const float* Wo  = (const float*)d_in[8];
    const float* bo  = (const float*)d_in[9];
    float* out = (float*)d_out;

    char* ws = (char*)d_ws;
    float* wcomb = (float*)ws;                                   // 256 f32
    float* vsb   = (float*)(ws + 1024);                          // 1 f32
    u16*   qkbuf = (u16*)(ws + 4096);                            // 16384*256 bf16 = 8 MiB
    float* vsmap = (float*)(ws + 4096 + (size_t)NP_ * C_ * 2);   // 16384 f32

    k0_combine<<<1, 256, 0, stream>>>(Wv, Wo, bv, wcomb, vsb);
    k1_proj<<<NP_ / 64, 256, 0, stream>>>(x, Wq, bq, Wk, bk, wcomb, vsb, qkbuf, vsmap);
    k2_attn<<<NP_ / 4, 256, 0, stream>>>(off, qkbuf, vsmap, bo, out);
}

// Round 5
// 95.104 us; speedup vs baseline: 1.7216x; 1.2230x over previous
//
#include <hip/hip_runtime.h>

typedef unsigned short u16;
typedef unsigned int u32;

#define B_   4
#define C_   256
#define CI_  128
#define H_   64
#define W_   64
#define NPB_ 4096     // pixels per batch image
#define NP_  16384    // total pixels
#define K_   9        // 3x3 taps
#define MROWS_ 272    // 128 q + 128 k + 1 wcomb + 15 pad

typedef __attribute__((ext_vector_type(8))) __bf16 bf16x8_t;
typedef __attribute__((ext_vector_type(4))) float f32x4_t;

__device__ __forceinline__ float bf2f(u16 u) {
    union { u32 i; float f; } x; x.i = ((u32)u) << 16; return x.f;
}
__device__ __forceinline__ float bf2f_lo(u32 w) {
    union { u32 i; float f; } x; x.i = w << 16; return x.f;
}
__device__ __forceinline__ float bf2f_hi(u32 w) {
    union { u32 i; float f; } x; x.i = w & 0xffff0000u; return x.f;
}
__device__ __forceinline__ u16 f2bf(float f) {  // round-to-nearest-even
    union { float f; u32 i; } x; x.f = f;
    u32 lsb = (x.i >> 16) & 1u;
    return (u16)((x.i + 0x7fffu + lsb) >> 16);
}
__device__ __forceinline__ void acc8(float* f, uint4 v, float w) {
    f[0] += w * bf2f_lo(v.x); f[1] += w * bf2f_hi(v.x);
    f[2] += w * bf2f_lo(v.y); f[3] += w * bf2f_hi(v.y);
    f[4] += w * bf2f_lo(v.z); f[5] += w * bf2f_hi(v.z);
    f[6] += w * bf2f_lo(v.w); f[7] += w * bf2f_hi(v.w);
}

// k0b: prepare Wbf[272][256] bf16 (q rows, k rows, wcomb row, zero pad) and
// bias_f32[272] (bq, bk, vsb=Wo·bv, zeros). One block per output row.
__global__ void k0b_prep(const float* __restrict__ Wq, const float* __restrict__ bq,
                         const float* __restrict__ Wk, const float* __restrict__ bk,
                         const float* __restrict__ Wv, const float* __restrict__ bv,
                         const float* __restrict__ Wo,
                         u16* __restrict__ Wbf, float* __restrict__ bias) {
    const int o = blockIdx.x;   // 0..271
    const int c = threadIdx.x;  // 0..255
    if (o < 128) {
        Wbf[o * C_ + c] = f2bf(Wq[o * C_ + c]);
        if (c == 0) bias[o] = bq[o];
    } else if (o < 256) {
        Wbf[o * C_ + c] = f2bf(Wk[(o - 128) * C_ + c]);
        if (c == 0) bias[o] = bk[o - 128];
    } else if (o == 256) {
        float s = 0.f;
        #pragma unroll 8
        for (int oo = 0; oo < CI_; ++oo)
            s += Wo[oo] * Wv[oo * C_ + c];
        Wbf[o * C_ + c] = f2bf(s);
        if (c == 0) {
            float ts = 0.f;
            #pragma unroll 8
            for (int oo = 0; oo < CI_; ++oo) ts += Wo[oo] * bv[oo];
            bias[256] = ts;
        }
    } else {
        Wbf[o * C_ + c] = 0;
        if (c == 0) bias[o] = 0.f;
    }
}

// k1: MFMA GEMM, no LDS. Block = 64 px, wave w = 16-px N-subtile.
// A-frags (W, bf16) read dwordx4 from L2-resident Wbf; B-frags (x) are 8
// coalesced f32 scalar loads per k-step. D lane map: col(px)=l&15,
// row(o)=(l>>4)*4+r (HW-verified m89). acc row 256 = vs (wcomb-folded).
__global__ __launch_bounds__(256) void k1_proj(
    const float* __restrict__ x, const u16* __restrict__ Wbf,
    const float* __restrict__ bias,
    u16* __restrict__ qk, float* __restrict__ vs) {
    const int t = threadIdx.x;
    const int l = t & 63;
    const int w = t >> 6;
    const int lane16 = l & 15;
    const int g = l >> 4;
    const int p0 = blockIdx.x * 64;                      // global pixel base
    const int b = p0 >> 12;
    const int px = p0 + w * 16 + lane16;                 // this lane's global pixel
    const int pin = (px & 4095);
    const float* xb = x + (size_t)b * C_ * NPB_ + pin;   // + c*NPB_

    f32x4_t acc[17];
    #pragma unroll
    for (int mt = 0; mt < 17; ++mt) {
        #pragma unroll
        for (int r = 0; r < 4; ++r)
            acc[mt][r] = bias[mt * 16 + g * 4 + r];
    }

    #pragma unroll
    for (int kk = 0; kk < 8; ++kk) {                     // K = 256, step 32
        const int c0 = kk * 32 + g * 8;
        bf16x8_t bv;
        #pragma unroll
        for (int e = 0; e < 8; ++e)
            bv[e] = (__bf16)xb[(size_t)(c0 + e) * NPB_];
        const u16* arow = Wbf + c0 + lane16 * C_;
        #pragma unroll
        for (int mt = 0; mt < 17; ++mt) {
            const bf16x8_t av = *reinterpret_cast<const bf16x8_t*>(arow + mt * 16 * C_);
            acc[mt] = __builtin_amdgcn_mfma_f32_16x16x32_bf16(av, bv, acc[mt], 0, 0, 0);
        }
    }

    // epilogue: qk rows are channel-last per pixel
    u16* qrow = qk + (size_t)px * C_;
    #pragma unroll
    for (int mt = 0; mt < 16; ++mt) {
        u32* dst = reinterpret_cast<u32*>(qrow + mt * 16 + g * 4);
        dst[0] = (u32)f2bf(acc[mt][0]) | ((u32)f2bf(acc[mt][1]) << 16);
        dst[1] = (u32)f2bf(acc[mt][2]) | ((u32)f2bf(acc[mt][3]) << 16);
    }
    if (g == 0) vs[px] = acc[16][0];   // row 256 = vs
}

// k2: one wave per pixel. lane l: tap = l&15 (A-row j of ku AND B-col i of qu),
// channel slice c = step*32 + (l>>4)*8 + e. A/B share the (lane,elem)->k map, so
// any HW k-permutation cancels; C/D layout is the HW-verified col=l&15,
// row=(l>>4)*4+reg (m89). S = ku^T(.)qu via 4x mfma_f32_16x16x32_bf16.
__global__ __launch_bounds__(256) void k2_attn(
    const float* __restrict__ off, const u16* __restrict__ qk,
    const float* __restrict__ vs, const float* __restrict__ bo,
    float* __restrict__ out) {
    const int t = threadIdx.x;
    const int l = t & 63;
    const int pixel = blockIdx.x * 4 + (t >> 6);
    const int b = pixel >> 12;
    const int rem = pixel & 4095;
    const int y = rem >> 6, xx = rem & 63;
    const int tap = l & 15;
    const int g = l >> 4;

    float fq[32], fk[32];   // [s*8+e] bilinear-accumulated q/k channels (f32)
    #pragma unroll
    for (int e = 0; e < 32; ++e) { fq[e] = 0.f; fk[e] = 0.f; }
    float vsu_t = 0.f;

    if (tap < K_) {
        const float* offb = off + ((size_t)b * (2 * K_) + 2 * tap) * NPB_ + rem;
        const float oy = offb[0];
        const float ox = offb[NPB_];
        const float py = (float)(y + tap / 3 - 1) + oy;
        const float px = (float)(xx + tap % 3 - 1) + ox;
        const float fy0 = floorf(py), fx0 = floorf(px);
        const float fy = py - fy0, fx = px - fx0;
        const int y0 = (int)fy0, x0 = (int)fx0;
        const u16* qkb = qk + ((size_t)(b << 12)) * C_ + g * 8;
        const float* vsm = vs + (b << 12);
        #pragma unroll
        for (int dy = 0; dy < 2; ++dy) {
            const int yi = y0 + dy;
            if (yi < 0 || yi >= H_) continue;       // zero padding
            const float wy = dy ? fy : 1.f - fy;
            #pragma unroll
            for (int dx = 0; dx < 2; ++dx) {
                const int xi = x0 + dx;
                if (xi < 0 || xi >= W_) continue;
                const float w = wy * (dx ? fx : 1.f - fx);
                const int pp = yi * W_ + xi;
                const u16* base = qkb + (size_t)pp * C_;
                #pragma unroll
                for (int s = 0; s < 4; ++s) {
                    const uint4 qv = *reinterpret_cast<const uint4*>(base + s * 32);
                    const uint4 kv = *reinterpret_cast<const uint4*>(base + CI_ + s * 32);
                    acc8(&fq[s * 8], qv, w);
                    acc8(&fk[s * 8], kv, w);
                }
                vsu_t += w * vsm[pp];
            }
        }
    }

    // 4 MFMA steps: acc[r] = S[i = tap][j = g*4 + r]
    f32x4_t acc = {0.f, 0.f, 0.f, 0.f};
    #pragma unroll
    for (int s = 0; s < 4; ++s) {
        bf16x8_t av, bv;
        #pragma unroll
        for (int e = 0; e < 8; ++e) {
            av[e] = (__bf16)fk[s * 8 + e];   // A = ku (rows j)
            bv[e] = (__bf16)fq[s * 8 + e];   // B = qu (cols i)
        }
        acc = __builtin_amdgcn_mfma_f32_16x16x32_bf16(av, bv, acc, 0, 0, 0);
    }

    // softmax over j for fixed i = tap; j spread across lane groups (stride-16 lanes)
    float mx = -1e30f;
    #pragma unroll
    for (int r = 0; r < 4; ++r) {
        const int j = g * 4 + r;
        if (j < K_) mx = fmaxf(mx, acc[r]);
    }
    mx = fmaxf(mx, __shfl_xor(mx, 16, 64));
    mx = fmaxf(mx, __shfl_xor(mx, 32, 64));

    float vj[4];
    #pragma unroll
    for (int r = 0; r < 4; ++r) vj[r] = __shfl(vsu_t, g * 4 + r, 64);  // vsu[j] from lane j

    float den = 0.f, num = 0.f;
    #pragma unroll
    for (int r = 0; r < 4; ++r) {
        const int j = g * 4 + r;
        if (j < K_) {
            const float e = __expf(acc[r] - mx);
            den += e;
            num += e * vj[r];
        }
    }
    den += __shfl_xor(den, 16, 64); den += __shfl_xor(den, 32, 64);
    num += __shfl_xor(num, 16, 64); num += __shfl_xor(num, 32, 64);

    if (l < K_) {
        const float z = num / den + bo[0];
        out[(size_t)b * K_ * NPB_ + (size_t)l * NPB_ + rem] = 1.f / (1.f + __expf(-z));
    }
}

extern "C" void kernel_launch(void* const* d_in, const int* in_sizes, int n_in,
                              void* d_out, int out_size, void* d_ws, size_t ws_size,
                              hipStream_t stream) {
    const float* x   = (const float*)d_in[0];
    const float* off = (const float*)d_in[1];
    const float* Wq  = (const float*)d_in[2];
    const float* bq  = (const float*)d_in[3];
    const float* Wk  = (const float*)d_in[4];
    const float* bk  = (const float*)d_in[5];
    const float* Wv  = (const float*)d_in[6];
    const float* bv  = (const float*)d_in[7];
    const float* Wo  = (const float*)d_in[8];
    const float* bo  = (const float*)d_in[9];
    float* out = (float*)d_out;

    char* ws = (char*)d_ws;
    u16*   qkbuf = (u16*)(ws + 4096);                 // 16384*256 bf16 = 8 MiB
    float* vsmap = (float*)(ws + 4096 + 8388608);     // 16384 f32 = 64 KiB
    u16*   Wbf   = (u16*)(ws + 4096 + 8388608 + 65536);        // 272*256 bf16
    float* bias  = (float*)(ws + 4096 + 8388608 + 65536 + 139264);  // 272 f32

    k0b_prep<<<MROWS_, 256, 0, stream>>>(Wq, bq, Wk, bk, Wv, bv, Wo, Wbf, bias);
    k1_proj<<<NP_ / 64, 256, 0, stream>>>(x, Wbf, bias, qkbuf, vsmap);
    k2_attn<<<NP_ / 4, 256, 0, stream>>>(off, qkbuf, vsmap, bo, out);
}

// Round 6
// 85.100 us; speedup vs baseline: 1.9240x; 1.1176x over previous
//
#include <hip/hip_runtime.h>

typedef unsigned short u16;
typedef unsigned int u32;

#define B_   4
#define C_   256
#define CI_  128
#define H_   64
#define W_   64
#define NPB_ 4096     // pixels per batch image
#define NP_  16384    // total pixels
#define K_   9        // 3x3 taps
#define MROWS_ 272    // 128 q + 128 k + 1 wcomb + 15 pad

typedef __attribute__((ext_vector_type(8))) __bf16 bf16x8_t;
typedef __attribute__((ext_vector_type(4))) float f32x4_t;
typedef __attribute__((ext_vector_type(2))) float f32x2_t;

__device__ __forceinline__ float bf2f(u16 u) {
    union { u32 i; float f; } x; x.i = ((u32)u) << 16; return x.f;
}
__device__ __forceinline__ float bf2f_lo(u32 w) {
    union { u32 i; float f; } x; x.i = w << 16; return x.f;
}
__device__ __forceinline__ float bf2f_hi(u32 w) {
    union { u32 i; float f; } x; x.i = w & 0xffff0000u; return x.f;
}
__device__ __forceinline__ u16 f2bf(float f) {  // round-to-nearest-even
    union { float f; u32 i; } x; x.f = f;
    u32 lsb = (x.i >> 16) & 1u;
    return (u16)((x.i + 0x7fffu + lsb) >> 16);
}
// packed bilinear accumulate: 8 bf16 channels, f32x2 lanes -> v_pk_fma_f32
__device__ __forceinline__ void acc8p(f32x2_t* f, uint4 v, f32x2_t w2) {
    f32x2_t p;
    p.x = bf2f_lo(v.x); p.y = bf2f_hi(v.x); f[0] += w2 * p;
    p.x = bf2f_lo(v.y); p.y = bf2f_hi(v.y); f[1] += w2 * p;
    p.x = bf2f_lo(v.z); p.y = bf2f_hi(v.z); f[2] += w2 * p;
    p.x = bf2f_lo(v.w); p.y = bf2f_hi(v.w); f[3] += w2 * p;
}

// k0b: prepare Wbf[272][256] bf16 (q rows, k rows, wcomb row, zero pad) and
// bias_f32[272] (bq, bk, vsb=Wo·bv, zeros). One block per output row.
__global__ void k0b_prep(const float* __restrict__ Wq, const float* __restrict__ bq,
                         const float* __restrict__ Wk, const float* __restrict__ bk,
                         const float* __restrict__ Wv, const float* __restrict__ bv,
                         const float* __restrict__ Wo,
                         u16* __restrict__ Wbf, float* __restrict__ bias) {
    const int o = blockIdx.x;   // 0..271
    const int c = threadIdx.x;  // 0..255
    if (o < 128) {
        Wbf[o * C_ + c] = f2bf(Wq[o * C_ + c]);
        if (c == 0) bias[o] = bq[o];
    } else if (o < 256) {
        Wbf[o * C_ + c] = f2bf(Wk[(o - 128) * C_ + c]);
        if (c == 0) bias[o] = bk[o - 128];
    } else if (o == 256) {
        float s = 0.f;
        #pragma unroll 8
        for (int oo = 0; oo < CI_; ++oo)
            s += Wo[oo] * Wv[oo * C_ + c];
        Wbf[o * C_ + c] = f2bf(s);
        if (c == 0) {
            float ts = 0.f;
            #pragma unroll 8
            for (int oo = 0; oo < CI_; ++oo) ts += Wo[oo] * bv[oo];
            bias[256] = ts;
        }
    } else {
        Wbf[o * C_ + c] = 0;
        if (c == 0) bias[o] = 0.f;
    }
}

// k1: MFMA GEMM, no LDS. Block = 512 thr (8 waves) per 16-px tile; the 17
// M-tiles are split across waves ({2,..,2,3}) so waves/SIMD = 8 (was 1).
// All 8 waves read the same x B-fragments -> L1 reuse on the same CU; each
// wave's W rows (<=3 tiles = 24 KB) stay L1-resident. D lane map: col(px)=l&15,
// row(o)=(l>>4)*4+r (HW-verified m89; chain-verified by passing k1/k2).
__global__ __launch_bounds__(512) void k1_proj(
    const float* __restrict__ x, const u16* __restrict__ Wbf,
    const float* __restrict__ bias,
    u16* __restrict__ qk, float* __restrict__ vs) {
    const int t = threadIdx.x;
    const int l = t & 63;
    const int w = t >> 6;                                // wave 0..7
    const int lane16 = l & 15;
    const int g = l >> 4;
    const int px = blockIdx.x * 16 + lane16;             // this lane's global pixel
    const int b = px >> 12;
    const int pin = px & 4095;
    const float* xb = x + (size_t)b * C_ * NPB_ + pin;   // + c*NPB_

    const int mt0 = 2 * w;                               // first m-tile
    const int nmt = (w < 7) ? 2 : 3;                     // wave 7: 14,15,16

    f32x4_t acc[3];
    #pragma unroll
    for (int n = 0; n < 3; ++n) {
        const int mt = mt0 + n;
        #pragma unroll
        for (int r = 0; r < 4; ++r)
            acc[n][r] = (n < nmt) ? bias[mt * 16 + g * 4 + r] : 0.f;
    }

    #pragma unroll
    for (int kk = 0; kk < 8; ++kk) {                     // K = 256, step 32
        const int c0 = kk * 32 + g * 8;
        bf16x8_t bv;
        #pragma unroll
        for (int e = 0; e < 8; ++e)
            bv[e] = (__bf16)xb[(size_t)(c0 + e) * NPB_];
        const u16* arow = Wbf + c0 + (size_t)(mt0 * 16 + lane16) * C_;
        #pragma unroll
        for (int n = 0; n < 3; ++n) {
            if (n < nmt) {
                const bf16x8_t av = *reinterpret_cast<const bf16x8_t*>(arow + (size_t)n * 16 * C_);
                acc[n] = __builtin_amdgcn_mfma_f32_16x16x32_bf16(av, bv, acc[n], 0, 0, 0);
            }
        }
    }

    // epilogue: qk rows are channel-last per pixel
    u16* qrow = qk + (size_t)px * C_;
    #pragma unroll
    for (int n = 0; n < 3; ++n) {
        const int mt = mt0 + n;
        if (n < nmt && mt < 16) {
            u32* dst = reinterpret_cast<u32*>(qrow + mt * 16 + g * 4);
            dst[0] = (u32)f2bf(acc[n][0]) | ((u32)f2bf(acc[n][1]) << 16);
            dst[1] = (u32)f2bf(acc[n][2]) | ((u32)f2bf(acc[n][3]) << 16);
        }
    }
    if (w == 7 && g == 0) vs[px] = acc[2][0];   // row 256 = vs
}

// k2: one wave per pixel. lane l: tap = l&15 (A-row j of ku AND B-col i of qu),
// channel slice c = step*32 + (l>>4)*8 + e. A/B share the (lane,elem)->k map, so
// any HW k-permutation cancels; C/D layout is the HW-verified col=l&15,
// row=(l>>4)*4+reg (m89). S = ku^T(.)qu via 4x mfma_f32_16x16x32_bf16.
__global__ __launch_bounds__(256) void k2_attn(
    const float* __restrict__ off, const u16* __restrict__ qk,
    const float* __restrict__ vs, const float* __restrict__ bo,
    float* __restrict__ out) {
    const int t = threadIdx.x;
    const int l = t & 63;
    const int pixel = blockIdx.x * 4 + (t >> 6);
    const int b = pixel >> 12;
    const int rem = pixel & 4095;
    const int y = rem >> 6, xx = rem & 63;
    const int tap = l & 15;
    const int g = l >> 4;

    f32x2_t fq[16], fk[16];   // bilinear-accumulated q/k channels (f32x2 pairs)
    #pragma unroll
    for (int e = 0; e < 16; ++e) { fq[e] = (f32x2_t){0.f, 0.f}; fk[e] = (f32x2_t){0.f, 0.f}; }
    float vsu_t = 0.f;

    if (tap < K_) {
        const float* offb = off + ((size_t)b * (2 * K_) + 2 * tap) * NPB_ + rem;
        const float oy = offb[0];
        const float ox = offb[NPB_];
        const float py = (float)(y + tap / 3 - 1) + oy;
        const float px = (float)(xx + tap % 3 - 1) + ox;
        const float fy0 = floorf(py), fx0 = floorf(px);
        const float fy = py - fy0, fx = px - fx0;
        const int y0 = (int)fy0, x0 = (int)fx0;
        const u16* qkb = qk + ((size_t)(b << 12)) * C_ + g * 8;
        const float* vsm = vs + (b << 12);
        #pragma unroll
        for (int dy = 0; dy < 2; ++dy) {
            const int yi = y0 + dy;
            if (yi < 0 || yi >= H_) continue;       // zero padding
            const float wy = dy ? fy : 1.f - fy;
            #pragma unroll
            for (int dx = 0; dx < 2; ++dx) {
                const int xi = x0 + dx;
                if (xi < 0 || xi >= W_) continue;
                const float w = wy * (dx ? fx : 1.f - fx);
                const f32x2_t w2 = {w, w};
                const int pp = yi * W_ + xi;
                const u16* base = qkb + (size_t)pp * C_;
                #pragma unroll
                for (int s = 0; s < 4; ++s) {
                    const uint4 qv = *reinterpret_cast<const uint4*>(base + s * 32);
                    const uint4 kv = *reinterpret_cast<const uint4*>(base + CI_ + s * 32);
                    acc8p(&fq[s * 4], qv, w2);
                    acc8p(&fk[s * 4], kv, w2);
                }
                vsu_t += w * vsm[pp];
            }
        }
    }

    // 4 MFMA steps: acc[r] = S[i = tap][j = g*4 + r]
    f32x4_t acc = {0.f, 0.f, 0.f, 0.f};
    #pragma unroll
    for (int s = 0; s < 4; ++s) {
        bf16x8_t av, bv;
        #pragma unroll
        for (int e = 0; e < 4; ++e) {
            av[2 * e]     = (__bf16)fk[s * 4 + e].x;   // A = ku (rows j)
            av[2 * e + 1] = (__bf16)fk[s * 4 + e].y;
            bv[2 * e]     = (__bf16)fq[s * 4 + e].x;   // B = qu (cols i)
            bv[2 * e + 1] = (__bf16)fq[s * 4 + e].y;
        }
        acc = __builtin_amdgcn_mfma_f32_16x16x32_bf16(av, bv, acc, 0, 0, 0);
    }

    // softmax over j for fixed i = tap; j spread across lane groups (stride-16 lanes)
    float mx = -1e30f;
    #pragma unroll
    for (int r = 0; r < 4; ++r) {
        const int j = g * 4 + r;
        if (j < K_) mx = fmaxf(mx, acc[r]);
    }
    mx = fmaxf(mx, __shfl_xor(mx, 16, 64));
    mx = fmaxf(mx, __shfl_xor(mx, 32, 64));

    float vj[4];
    #pragma unroll
    for (int r = 0; r < 4; ++r) vj[r] = __shfl(vsu_t, g * 4 + r, 64);  // vsu[j] from lane j

    float den = 0.f, num = 0.f;
    #pragma unroll
    for (int r = 0; r < 4; ++r) {
        const int j = g * 4 + r;
        if (j < K_) {
            const float e = __expf(acc[r] - mx);
            den += e;
            num += e * vj[r];
        }
    }
    den += __shfl_xor(den, 16, 64); den += __shfl_xor(den, 32, 64);
    num += __shfl_xor(num, 16, 64); num += __shfl_xor(num, 32, 64);

    if (l < K_) {
        const float z = num / den + bo[0];
        out[(size_t)b * K_ * NPB_ + (size_t)l * NPB_ + rem] = 1.f / (1.f + __expf(-z));
    }
}

extern "C" void kernel_launch(void* const* d_in, const int* in_sizes, int n_in,
                              void* d_out, int out_size, void* d_ws, size_t ws_size,
                              hipStream_t stream) {
    const float* x   = (const float*)d_in[0];
    const float* off = (const float*)d_in[1];
    const float* Wq  = (const float*)d_in[2];
    const float* bq  = (const float*)d_in[3];
    const float* Wk  = (const float*)d_in[4];
    const float* bk  = (const float*)d_in[5];
    const float* Wv  = (const float*)d_in[6];
    const float* bv  = (const float*)d_in[7];
    const float* Wo  = (const float*)d_in[8];
    const float* bo  = (const float*)d_in[9];
    float* out = (float*)d_out;

    char* ws = (char*)d_ws;
    u16*   qkbuf = (u16*)(ws + 4096);                 // 16384*256 bf16 = 8 MiB
    float* vsmap = (float*)(ws + 4096 + 8388608);     // 16384 f32 = 64 KiB
    u16*   Wbf   = (u16*)(ws + 4096 + 8388608 + 65536);        // 272*256 bf16
    float* bias  = (float*)(ws + 4096 + 8388608 + 65536 + 139264);  // 272 f32

    k0b_prep<<<MROWS_, 256, 0, stream>>>(Wq, bq, Wk, bk, Wv, bv, Wo, Wbf, bias);
    k1_proj<<<NP_ / 16, 512, 0, stream>>>(x, Wbf, bias, qkbuf, vsmap);
    k2_attn<<<NP_ / 4, 256, 0, stream>>>(off, qkbuf, vsmap, bo, out);
}

// Round 7
// 80.782 us; speedup vs baseline: 2.0268x; 1.0535x over previous
//
#include <hip/hip_runtime.h>

typedef unsigned short u16;
typedef unsigned int u32;

#define B_   4
#define C_   256
#define CI_  128
#define H_   64
#define W_   64
#define NPB_ 4096     // pixels per batch image
#define NP_  16384    // total pixels
#define K_   9        // 3x3 taps
#define MROWS_ 272    // 128 q + 128 k + 1 wcomb + 15 pad

typedef __attribute__((ext_vector_type(8))) __bf16 bf16x8_t;
typedef __attribute__((ext_vector_type(4))) float f32x4_t;
typedef __attribute__((ext_vector_type(2))) float f32x2_t;

__device__ __forceinline__ float bf2f(u16 u) {
    union { u32 i; float f; } x; x.i = ((u32)u) << 16; return x.f;
}
__device__ __forceinline__ float bf2f_lo(u32 w) {
    union { u32 i; float f; } x; x.i = w << 16; return x.f;
}
__device__ __forceinline__ float bf2f_hi(u32 w) {
    union { u32 i; float f; } x; x.i = w & 0xffff0000u; return x.f;
}
__device__ __forceinline__ u16 f2bf(float f) {  // round-to-nearest-even
    union { float f; u32 i; } x; x.f = f;
    u32 lsb = (x.i >> 16) & 1u;
    return (u16)((x.i + 0x7fffu + lsb) >> 16);
}
// packed bilinear accumulate: 8 bf16 channels, f32x2 lanes -> v_pk_fma_f32
__device__ __forceinline__ void acc8p(f32x2_t* f, uint4 v, f32x2_t w2) {
    f32x2_t p;
    p.x = bf2f_lo(v.x); p.y = bf2f_hi(v.x); f[0] += w2 * p;
    p.x = bf2f_lo(v.y); p.y = bf2f_hi(v.y); f[1] += w2 * p;
    p.x = bf2f_lo(v.z); p.y = bf2f_hi(v.z); f[2] += w2 * p;
    p.x = bf2f_lo(v.w); p.y = bf2f_hi(v.w); f[3] += w2 * p;
}

// k0b: prepare Wbf[272][256] bf16 (q rows, k rows, wcomb row, zero pad) and
// bias_f32[272] (bq, bk, vsb=Wo·bv, zeros). One block per output row.
__global__ void k0b_prep(const float* __restrict__ Wq, const float* __restrict__ bq,
                         const float* __restrict__ Wk, const float* __restrict__ bk,
                         const float* __restrict__ Wv, const float* __restrict__ bv,
                         const float* __restrict__ Wo,
                         u16* __restrict__ Wbf, float* __restrict__ bias) {
    const int o = blockIdx.x;   // 0..271
    const int c = threadIdx.x;  // 0..255
    if (o < 128) {
        Wbf[o * C_ + c] = f2bf(Wq[o * C_ + c]);
        if (c == 0) bias[o] = bq[o];
    } else if (o < 256) {
        Wbf[o * C_ + c] = f2bf(Wk[(o - 128) * C_ + c]);
        if (c == 0) bias[o] = bk[o - 128];
    } else if (o == 256) {
        float s = 0.f;
        #pragma unroll 8
        for (int oo = 0; oo < CI_; ++oo)
            s += Wo[oo] * Wv[oo * C_ + c];
        Wbf[o * C_ + c] = f2bf(s);
        if (c == 0) {
            float ts = 0.f;
            #pragma unroll 8
            for (int oo = 0; oo < CI_; ++oo) ts += Wo[oo] * bv[oo];
            bias[256] = ts;
        }
    } else {
        Wbf[o * C_ + c] = 0;
        if (c == 0) bias[o] = 0.f;
    }
}

// k1: MFMA GEMM, no LDS. Block = 512 thr (8 waves) per 16-px tile; the 17
// M-tiles are split across waves ({2,..,2,3}) so waves/SIMD = 8. D lane map:
// col(px)=l&15, row(o)=(l>>4)*4+r (HW-verified m89; chain-verified passing).
__global__ __launch_bounds__(512) void k1_proj(
    const float* __restrict__ x, const u16* __restrict__ Wbf,
    const float* __restrict__ bias,
    u16* __restrict__ qk, float* __restrict__ vs) {
    const int t = threadIdx.x;
    const int l = t & 63;
    const int w = t >> 6;                                // wave 0..7
    const int lane16 = l & 15;
    const int g = l >> 4;
    const int px = blockIdx.x * 16 + lane16;             // this lane's global pixel
    const int b = px >> 12;
    const int pin = px & 4095;
    const float* xb = x + (size_t)b * C_ * NPB_ + pin;   // + c*NPB_

    const int mt0 = 2 * w;                               // first m-tile
    const int nmt = (w < 7) ? 2 : 3;                     // wave 7: 14,15,16

    f32x4_t acc[3];
    #pragma unroll
    for (int n = 0; n < 3; ++n) {
        const int mt = mt0 + n;
        #pragma unroll
        for (int r = 0; r < 4; ++r)
            acc[n][r] = (n < nmt) ? bias[mt * 16 + g * 4 + r] : 0.f;
    }

    #pragma unroll
    for (int kk = 0; kk < 8; ++kk) {                     // K = 256, step 32
        const int c0 = kk * 32 + g * 8;
        bf16x8_t bv;
        #pragma unroll
        for (int e = 0; e < 8; ++e)
            bv[e] = (__bf16)xb[(size_t)(c0 + e) * NPB_];
        const u16* arow = Wbf + c0 + (size_t)(mt0 * 16 + lane16) * C_;
        #pragma unroll
        for (int n = 0; n < 3; ++n) {
            if (n < nmt) {
                const bf16x8_t av = *reinterpret_cast<const bf16x8_t*>(arow + (size_t)n * 16 * C_);
                acc[n] = __builtin_amdgcn_mfma_f32_16x16x32_bf16(av, bv, acc[n], 0, 0, 0);
            }
        }
    }

    // epilogue: qk rows are channel-last per pixel
    u16* qrow = qk + (size_t)px * C_;
    #pragma unroll
    for (int n = 0; n < 3; ++n) {
        const int mt = mt0 + n;
        if (n < nmt && mt < 16) {
            u32* dst = reinterpret_cast<u32*>(qrow + mt * 16 + g * 4);
            dst[0] = (u32)f2bf(acc[n][0]) | ((u32)f2bf(acc[n][1]) << 16);
            dst[1] = (u32)f2bf(acc[n][2]) | ((u32)f2bf(acc[n][3]) << 16);
        }
    }
    if (w == 7 && g == 0) vs[px] = acc[2][0];   // row 256 = vs
}

// k2: one wave per pixel. lane l: tap = min(l&15, 8) (A-row j of ku AND B-col
// i of qu), channel slice c = s*32 + (l>>4)*8 + e. BRANCHLESS gather: corner
// validity folded into weight (w*valid == ref's valid-mask on gathered value),
// addresses clamped; pad-lanes clone tap 8 (rows/cols >=9 never read). All 32
// corner loads are unguarded -> compiler can pipeline across the 4 s-phases.
// A/B share the (lane,elem)->k map so HW k-permutation cancels; C/D layout is
// HW-verified col=l&15, row=(l>>4)*4+reg (m89).
__global__ __launch_bounds__(256) void k2_attn(
    const float* __restrict__ off, const u16* __restrict__ qk,
    const float* __restrict__ vs, const float* __restrict__ bo,
    float* __restrict__ out) {
    const int t = threadIdx.x;
    const int l = t & 63;
    const int pixel = blockIdx.x * 4 + (t >> 6);
    const int b = pixel >> 12;
    const int rem = pixel & 4095;
    const int y = rem >> 6, xx = rem & 63;
    const int l16 = l & 15;
    const int tap = (l16 < K_) ? l16 : (K_ - 1);
    const int g = l >> 4;

    const float* offb = off + ((size_t)b * (2 * K_) + 2 * tap) * NPB_ + rem;
    const float oy = offb[0];
    const float ox = offb[NPB_];
    const float py = (float)(y + tap / 3 - 1) + oy;
    const float px = (float)(xx + tap % 3 - 1) + ox;
    const float fy0 = floorf(py), fx0 = floorf(px);
    const float fy = py - fy0, fx = px - fx0;
    const int y0 = (int)fy0, x0 = (int)fx0;

    const u16* qkb = qk + ((size_t)(b << 12)) * C_ + g * 8;
    const float* vsm = vs + (b << 12);

    // 4 corner weights (validity-masked) + clamped base pointers
    float wgt[4];
    int ppc[4];
    const u16* bp[4];
    #pragma unroll
    for (int c = 0; c < 4; ++c) {
        const int dy = c >> 1, dx = c & 1;
        const int yi = y0 + dy, xi = x0 + dx;
        const float wv = (dy ? fy : 1.f - fy) * (dx ? fx : 1.f - fx);
        const int ok = (yi >= 0) & (yi < H_) & (xi >= 0) & (xi < W_);
        const int yc = min(max(yi, 0), H_ - 1);
        const int xc = min(max(xi, 0), W_ - 1);
        ppc[c] = yc * W_ + xc;
        wgt[c] = ok ? wv : 0.f;
        bp[c] = qkb + (size_t)ppc[c] * C_;
    }

    f32x2_t fq[16], fk[16];   // bilinear-accumulated q/k channels (f32x2 pairs)
    #pragma unroll
    for (int e = 0; e < 16; ++e) { fq[e] = (f32x2_t){0.f, 0.f}; fk[e] = (f32x2_t){0.f, 0.f}; }

    #pragma unroll
    for (int s = 0; s < 4; ++s) {
        uint4 qv[4], kv[4];
        #pragma unroll
        for (int c = 0; c < 4; ++c) {
            qv[c] = *reinterpret_cast<const uint4*>(bp[c] + s * 32);
            kv[c] = *reinterpret_cast<const uint4*>(bp[c] + CI_ + s * 32);
        }
        #pragma unroll
        for (int c = 0; c < 4; ++c) {
            const f32x2_t w2 = {wgt[c], wgt[c]};
            acc8p(&fq[s * 4], qv[c], w2);
            acc8p(&fk[s * 4], kv[c], w2);
        }
    }
    const float vsu_t = wgt[0] * vsm[ppc[0]] + wgt[1] * vsm[ppc[1]] +
                        wgt[2] * vsm[ppc[2]] + wgt[3] * vsm[ppc[3]];

    // 4 MFMA steps: acc[r] = S[i = tap][j = g*4 + r]
    f32x4_t acc = {0.f, 0.f, 0.f, 0.f};
    #pragma unroll
    for (int s = 0; s < 4; ++s) {
        bf16x8_t av, bv;
        #pragma unroll
        for (int e = 0; e < 4; ++e) {
            av[2 * e]     = (__bf16)fk[s * 4 + e].x;   // A = ku (rows j)
            av[2 * e + 1] = (__bf16)fk[s * 4 + e].y;
            bv[2 * e]     = (__bf16)fq[s * 4 + e].x;   // B = qu (cols i)
            bv[2 * e + 1] = (__bf16)fq[s * 4 + e].y;
        }
        acc = __builtin_amdgcn_mfma_f32_16x16x32_bf16(av, bv, acc, 0, 0, 0);
    }

    // softmax over j for fixed i = tap; j spread across lane groups (stride-16 lanes)
    float mx = -1e30f;
    #pragma unroll
    for (int r = 0; r < 4; ++r) {
        const int j = g * 4 + r;
        if (j < K_) mx = fmaxf(mx, acc[r]);
    }
    mx = fmaxf(mx, __shfl_xor(mx, 16, 64));
    mx = fmaxf(mx, __shfl_xor(mx, 32, 64));

    float vj[4];
    #pragma unroll
    for (int r = 0; r < 4; ++r) vj[r] = __shfl(vsu_t, g * 4 + r, 64);  // vsu[j] from lane j

    float den = 0.f, num = 0.f;
    #pragma unroll
    for (int r = 0; r < 4; ++r) {
        const int j = g * 4 + r;
        if (j < K_) {
            const float e = __expf(acc[r] - mx);
            den += e;
            num += e * vj[r];
        }
    }
    den += __shfl_xor(den, 16, 64); den += __shfl_xor(den, 32, 64);
    num += __shfl_xor(num, 16, 64); num += __shfl_xor(num, 32, 64);

    if (l < K_) {
        const float z = num / den + bo[0];
        out[(size_t)b * K_ * NPB_ + (size_t)l * NPB_ + rem] = 1.f / (1.f + __expf(-z));
    }
}

extern "C" void kernel_launch(void* const* d_in, const int* in_sizes, int n_in,
                              void* d_out, int out_size, void* d_ws, size_t ws_size,
                              hipStream_t stream) {
    const float* x   = (const float*)d_in[0];
    const float* off = (const float*)d_in[1];
    const float* Wq  = (const float*)d_in[2];
    const float* bq  = (const float*)d_in[3];
    const float* Wk  = (const float*)d_in[4];
    const float* bk  = (const float*)d_in[5];
    const float* Wv  = (const float*)d_in[6];
    const float* bv  = (const float*)d_in[7];
    const float* Wo  = (const float*)d_in[8];
    const float* bo  = (const float*)d_in[9];
    float* out = (float*)d_out;

    char* ws = (char*)d_ws;
    u16*   qkbuf = (u16*)(ws + 4096);                 // 16384*256 bf16 = 8 MiB
    float* vsmap = (float*)(ws + 4096 + 8388608);     // 16384 f32 = 64 KiB
    u16*   Wbf   = (u16*)(ws + 4096 + 8388608 + 65536);        // 272*256 bf16
    float* bias  = (float*)(ws + 4096 + 8388608 + 65536 + 139264);  // 272 f32

    k0b_prep<<<MROWS_, 256, 0, stream>>>(Wq, bq, Wk, bk, Wv, bv, Wo, Wbf, bias);
    k1_proj<<<NP_ / 16, 512, 0, stream>>>(x, Wbf, bias, qkbuf, vsmap);
    k2_attn<<<NP_ / 4, 256, 0, stream>>>(off, qkbuf, vsmap, bo, out);
}

// Round 8
// 79.863 us; speedup vs baseline: 2.0501x; 1.0115x over previous
//
#include <hip/hip_runtime.h>

typedef unsigned short u16;
typedef unsigned int u32;

#define B_   4
#define C_   256
#define CI_  128
#define H_   64
#define W_   64
#define NPB_ 4096     // pixels per batch image
#define NP_  16384    // total pixels
#define K_   9        // 3x3 taps
#define MROWS_ 272    // 128 q + 128 k + 1 wcomb + 15 pad

typedef __attribute__((ext_vector_type(8))) __bf16 bf16x8_t;
typedef __attribute__((ext_vector_type(4))) float f32x4_t;
typedef __attribute__((ext_vector_type(2))) float f32x2_t;

__device__ __forceinline__ float bf2f(u16 u) {
    union { u32 i; float f; } x; x.i = ((u32)u) << 16; return x.f;
}
__device__ __forceinline__ float bf2f_lo(u32 w) {
    union { u32 i; float f; } x; x.i = w << 16; return x.f;
}
__device__ __forceinline__ float bf2f_hi(u32 w) {
    union { u32 i; float f; } x; x.i = w & 0xffff0000u; return x.f;
}
__device__ __forceinline__ u16 f2bf(float f) {  // round-to-nearest-even
    union { float f; u32 i; } x; x.f = f;
    u32 lsb = (x.i >> 16) & 1u;
    return (u16)((x.i + 0x7fffu + lsb) >> 16);
}
// packed bilinear accumulate: 8 bf16 channels, f32x2 lanes -> v_pk_fma_f32
__device__ __forceinline__ void acc8p(f32x2_t* f, uint4 v, f32x2_t w2) {
    f32x2_t p;
    p.x = bf2f_lo(v.x); p.y = bf2f_hi(v.x); f[0] += w2 * p;
    p.x = bf2f_lo(v.y); p.y = bf2f_hi(v.y); f[1] += w2 * p;
    p.x = bf2f_lo(v.z); p.y = bf2f_hi(v.z); f[2] += w2 * p;
    p.x = bf2f_lo(v.w); p.y = bf2f_hi(v.w); f[3] += w2 * p;
}

// k0b: prepare Wbf[272][256] bf16 (q rows, k rows, wcomb row, zero pad) and
// bias_f32[272] (bq, bk, vsb=Wo·bv, zeros). One block per output row.
__global__ void k0b_prep(const float* __restrict__ Wq, const float* __restrict__ bq,
                         const float* __restrict__ Wk, const float* __restrict__ bk,
                         const float* __restrict__ Wv, const float* __restrict__ bv,
                         const float* __restrict__ Wo,
                         u16* __restrict__ Wbf, float* __restrict__ bias) {
    const int o = blockIdx.x;   // 0..271
    const int c = threadIdx.x;  // 0..255
    if (o < 128) {
        Wbf[o * C_ + c] = f2bf(Wq[o * C_ + c]);
        if (c == 0) bias[o] = bq[o];
    } else if (o < 256) {
        Wbf[o * C_ + c] = f2bf(Wk[(o - 128) * C_ + c]);
        if (c == 0) bias[o] = bk[o - 128];
    } else if (o == 256) {
        float s = 0.f;
        #pragma unroll 8
        for (int oo = 0; oo < CI_; ++oo)
            s += Wo[oo] * Wv[oo * C_ + c];
        Wbf[o * C_ + c] = f2bf(s);
        if (c == 0) {
            float ts = 0.f;
            #pragma unroll 8
            for (int oo = 0; oo < CI_; ++oo) ts += Wo[oo] * bv[oo];
            bias[256] = ts;
        }
    } else {
        Wbf[o * C_ + c] = 0;
        if (c == 0) bias[o] = 0.f;
    }
}

// k1: MFMA GEMM, no LDS. Block = 512 thr (8 waves) per 16-px tile; the 17
// M-tiles are split across waves ({2,..,2,3}) so waves/SIMD = 8. D lane map:
// col(px)=l&15, row(o)=(l>>4)*4+r (HW-verified m89; chain-verified passing).
__global__ __launch_bounds__(512) void k1_proj(
    const float* __restrict__ x, const u16* __restrict__ Wbf,
    const float* __restrict__ bias,
    u16* __restrict__ qk, float* __restrict__ vs) {
    const int t = threadIdx.x;
    const int l = t & 63;
    const int w = t >> 6;                                // wave 0..7
    const int lane16 = l & 15;
    const int g = l >> 4;
    const int px = blockIdx.x * 16 + lane16;             // this lane's global pixel
    const int b = px >> 12;
    const int pin = px & 4095;
    const float* xb = x + (size_t)b * C_ * NPB_ + pin;   // + c*NPB_

    const int mt0 = 2 * w;                               // first m-tile
    const int nmt = (w < 7) ? 2 : 3;                     // wave 7: 14,15,16

    f32x4_t acc[3];
    #pragma unroll
    for (int n = 0; n < 3; ++n) {
        const int mt = mt0 + n;
        #pragma unroll
        for (int r = 0; r < 4; ++r)
            acc[n][r] = (n < nmt) ? bias[mt * 16 + g * 4 + r] : 0.f;
    }

    #pragma unroll
    for (int kk = 0; kk < 8; ++kk) {                     // K = 256, step 32
        const int c0 = kk * 32 + g * 8;
        bf16x8_t bv;
        #pragma unroll
        for (int e = 0; e < 8; ++e)
            bv[e] = (__bf16)xb[(size_t)(c0 + e) * NPB_];
        const u16* arow = Wbf + c0 + (size_t)(mt0 * 16 + lane16) * C_;
        #pragma unroll
        for (int n = 0; n < 3; ++n) {
            if (n < nmt) {
                const bf16x8_t av = *reinterpret_cast<const bf16x8_t*>(arow + (size_t)n * 16 * C_);
                acc[n] = __builtin_amdgcn_mfma_f32_16x16x32_bf16(av, bv, acc[n], 0, 0, 0);
            }
        }
    }

    // epilogue: qk rows are channel-last per pixel
    u16* qrow = qk + (size_t)px * C_;
    #pragma unroll
    for (int n = 0; n < 3; ++n) {
        const int mt = mt0 + n;
        if (n < nmt && mt < 16) {
            u32* dst = reinterpret_cast<u32*>(qrow + mt * 16 + g * 4);
            dst[0] = (u32)f2bf(acc[n][0]) | ((u32)f2bf(acc[n][1]) << 16);
            dst[1] = (u32)f2bf(acc[n][2]) | ((u32)f2bf(acc[n][3]) << 16);
        }
    }
    if (w == 7 && g == 0) vs[px] = acc[2][0];   // row 256 = vs
}

// k2: one wave per pixel. lane l: tap = min(l&15, 8) (A-row j of ku AND B-col
// i of qu), channel slice c = s*32 + (l>>4)*8 + e. Branchless gather (validity
// folded into weight == ref's valid-mask). THIS ROUND: all 32 corner loads are
// issued into register arrays BEFORE any consumption -> one vmcnt drain per
// wave instead of 4+ serialized latency rounds. A/B share the (lane,elem)->k
// map so HW k-permutation cancels; C/D: col=l&15, row=(l>>4)*4+reg (m89).
__global__ __launch_bounds__(256) void k2_attn(
    const float* __restrict__ off, const u16* __restrict__ qk,
    const float* __restrict__ vs, const float* __restrict__ bo,
    float* __restrict__ out) {
    const int t = threadIdx.x;
    const int l = t & 63;
    const int pixel = blockIdx.x * 4 + (t >> 6);
    const int b = pixel >> 12;
    const int rem = pixel & 4095;
    const int y = rem >> 6, xx = rem & 63;
    const int l16 = l & 15;
    const int tap = (l16 < K_) ? l16 : (K_ - 1);
    const int g = l >> 4;

    const float* offb = off + ((size_t)b * (2 * K_) + 2 * tap) * NPB_ + rem;
    const float oy = offb[0];
    const float ox = offb[NPB_];
    const float py = (float)(y + tap / 3 - 1) + oy;
    const float px = (float)(xx + tap % 3 - 1) + ox;
    const float fy0 = floorf(py), fx0 = floorf(px);
    const float fy = py - fy0, fx = px - fx0;
    const int y0 = (int)fy0, x0 = (int)fx0;

    const u16* qkb = qk + ((size_t)(b << 12)) * C_ + g * 8;
    const float* vsm = vs + (b << 12);

    // 4 corner weights (validity-masked) + clamped base pointers
    float wgt[4];
    int ppc[4];
    const u16* bp[4];
    #pragma unroll
    for (int c = 0; c < 4; ++c) {
        const int dy = c >> 1, dx = c & 1;
        const int yi = y0 + dy, xi = x0 + dx;
        const float wv = (dy ? fy : 1.f - fy) * (dx ? fx : 1.f - fx);
        const int ok = (yi >= 0) & (yi < H_) & (xi >= 0) & (xi < W_);
        const int yc = min(max(yi, 0), H_ - 1);
        const int xc = min(max(xi, 0), W_ - 1);
        ppc[c] = yc * W_ + xc;
        wgt[c] = ok ? wv : 0.f;
        bp[c] = qkb + (size_t)ppc[c] * C_;
    }

    // ---- issue ALL loads up front (static indices -> registers, max MLP) ----
    uint4 qv[4][4], kv[4][4];       // [corner][s-phase]
    #pragma unroll
    for (int c = 0; c < 4; ++c) {
        #pragma unroll
        for (int s = 0; s < 4; ++s) {
            qv[c][s] = *reinterpret_cast<const uint4*>(bp[c] + s * 32);
            kv[c][s] = *reinterpret_cast<const uint4*>(bp[c] + CI_ + s * 32);
        }
    }
    const float vsu_t = wgt[0] * vsm[ppc[0]] + wgt[1] * vsm[ppc[1]] +
                        wgt[2] * vsm[ppc[2]] + wgt[3] * vsm[ppc[3]];

    // ---- consume ----
    f32x2_t fq[16], fk[16];   // bilinear-accumulated q/k channels (f32x2 pairs)
    #pragma unroll
    for (int e = 0; e < 16; ++e) { fq[e] = (f32x2_t){0.f, 0.f}; fk[e] = (f32x2_t){0.f, 0.f}; }
    #pragma unroll
    for (int s = 0; s < 4; ++s) {
        #pragma unroll
        for (int c = 0; c < 4; ++c) {
            const f32x2_t w2 = {wgt[c], wgt[c]};
            acc8p(&fq[s * 4], qv[c][s], w2);
            acc8p(&fk[s * 4], kv[c][s], w2);
        }
    }

    // 4 MFMA steps: acc[r] = S[i = tap][j = g*4 + r]
    f32x4_t acc = {0.f, 0.f, 0.f, 0.f};
    #pragma unroll
    for (int s = 0; s < 4; ++s) {
        bf16x8_t av, bv;
        #pragma unroll
        for (int e = 0; e < 4; ++e) {
            av[2 * e]     = (__bf16)fk[s * 4 + e].x;   // A = ku (rows j)
            av[2 * e + 1] = (__bf16)fk[s * 4 + e].y;
            bv[2 * e]     = (__bf16)fq[s * 4 + e].x;   // B = qu (cols i)
            bv[2 * e + 1] = (__bf16)fq[s * 4 + e].y;
        }
        acc = __builtin_amdgcn_mfma_f32_16x16x32_bf16(av, bv, acc, 0, 0, 0);
    }

    // softmax over j for fixed i = tap; j spread across lane groups (stride-16 lanes)
    float mx = -1e30f;
    #pragma unroll
    for (int r = 0; r < 4; ++r) {
        const int j = g * 4 + r;
        if (j < K_) mx = fmaxf(mx, acc[r]);
    }
    mx = fmaxf(mx, __shfl_xor(mx, 16, 64));
    mx = fmaxf(mx, __shfl_xor(mx, 32, 64));

    float vj[4];
    #pragma unroll
    for (int r = 0; r < 4; ++r) vj[r] = __shfl(vsu_t, g * 4 + r, 64);  // vsu[j] from lane j

    float den = 0.f, num = 0.f;
    #pragma unroll
    for (int r = 0; r < 4; ++r) {
        const int j = g * 4 + r;
        if (j < K_) {
            const float e = __expf(acc[r] - mx);
            den += e;
            num += e * vj[r];
        }
    }
    den += __shfl_xor(den, 16, 64); den += __shfl_xor(den, 32, 64);
    num += __shfl_xor(num, 16, 64); num += __shfl_xor(num, 32, 64);

    if (l < K_) {
        const float z = num / den + bo[0];
        out[(size_t)b * K_ * NPB_ + (size_t)l * NPB_ + rem] = 1.f / (1.f + __expf(-z));
    }
}

extern "C" void kernel_launch(void* const* d_in, const int* in_sizes, int n_in,
                              void* d_out, int out_size, void* d_ws, size_t ws_size,
                              hipStream_t stream) {
    const float* x   = (const float*)d_in[0];
    const float* off = (const float*)d_in[1];
    const float* Wq  = (const float*)d_in[2];
    const float* bq  = (const float*)d_in[3];
    const float* Wk  = (const float*)d_in[4];
    const float* bk  = (const float*)d_in[5];
    const float* Wv  = (const float*)d_in[6];
    const float* bv  = (const float*)d_in[7];
    const float* Wo  = (const float*)d_in[8];
    const float* bo  = (const float*)d_in[9];
    float* out = (float*)d_out;

    char* ws = (char*)d_ws;
    u16*   qkbuf = (u16*)(ws + 4096);                 // 16384*256 bf16 = 8 MiB
    float* vsmap = (float*)(ws + 4096 + 8388608);     // 16384 f32 = 64 KiB
    u16*   Wbf   = (u16*)(ws + 4096 + 8388608 + 65536);        // 272*256 bf16
    float* bias  = (float*)(ws + 4096 + 8388608 + 65536 + 139264);  // 272 f32

    k0b_prep<<<MROWS_, 256, 0, stream>>>(Wq, bq, Wk, bk, Wv, bv, Wo, Wbf, bias);
    k1_proj<<<NP_ / 16, 512, 0, stream>>>(x, Wbf, bias, qkbuf, vsmap);
    k2_attn<<<NP_ / 4, 256, 0, stream>>>(off, qkbuf, vsmap, bo, out);
}

// Round 9
// 78.060 us; speedup vs baseline: 2.0975x; 1.0231x over previous
//
#include <hip/hip_runtime.h>

typedef unsigned short u16;
typedef unsigned int u32;

#define B_   4
#define C_   256
#define CI_  128
#define H_   64
#define W_   64
#define NPB_ 4096     // pixels per batch image
#define NP_  16384    // total pixels
#define K_   9        // 3x3 taps
#define MROWS_ 272    // 128 q + 128 k + 1 wcomb + 15 pad

typedef __attribute__((ext_vector_type(8))) __bf16 bf16x8_t;
typedef __attribute__((ext_vector_type(4))) float f32x4_t;
typedef __attribute__((ext_vector_type(2))) float f32x2_t;

__device__ __forceinline__ float bf2f(u16 u) {
    union { u32 i; float f; } x; x.i = ((u32)u) << 16; return x.f;
}
__device__ __forceinline__ float bf2f_lo(u32 w) {
    union { u32 i; float f; } x; x.i = w << 16; return x.f;
}
__device__ __forceinline__ float bf2f_hi(u32 w) {
    union { u32 i; float f; } x; x.i = w & 0xffff0000u; return x.f;
}
__device__ __forceinline__ u16 f2bf(float f) {  // round-to-nearest-even
    union { float f; u32 i; } x; x.f = f;
    u32 lsb = (x.i >> 16) & 1u;
    return (u16)((x.i + 0x7fffu + lsb) >> 16);
}
// packed bilinear accumulate: 8 bf16 channels, f32x2 lanes -> v_pk_fma_f32
__device__ __forceinline__ void acc8p(f32x2_t* f, uint4 v, f32x2_t w2) {
    f32x2_t p;
    p.x = bf2f_lo(v.x); p.y = bf2f_hi(v.x); f[0] += w2 * p;
    p.x = bf2f_lo(v.y); p.y = bf2f_hi(v.y); f[1] += w2 * p;
    p.x = bf2f_lo(v.z); p.y = bf2f_hi(v.z); f[2] += w2 * p;
    p.x = bf2f_lo(v.w); p.y = bf2f_hi(v.w); f[3] += w2 * p;
}

// k0b: prepare Wbf[272][256] bf16 (q rows, k rows, wcomb row, zero pad) and
// bias_f32[272] (bq, bk, vsb=Wo·bv, zeros). One block per output row.
__global__ void k0b_prep(const float* __restrict__ Wq, const float* __restrict__ bq,
                         const float* __restrict__ Wk, const float* __restrict__ bk,
                         const float* __restrict__ Wv, const float* __restrict__ bv,
                         const float* __restrict__ Wo,
                         u16* __restrict__ Wbf, float* __restrict__ bias) {
    const int o = blockIdx.x;   // 0..271
    const int c = threadIdx.x;  // 0..255
    if (o < 128) {
        Wbf[o * C_ + c] = f2bf(Wq[o * C_ + c]);
        if (c == 0) bias[o] = bq[o];
    } else if (o < 256) {
        Wbf[o * C_ + c] = f2bf(Wk[(o - 128) * C_ + c]);
        if (c == 0) bias[o] = bk[o - 128];
    } else if (o == 256) {
        float s = 0.f;
        #pragma unroll 8
        for (int oo = 0; oo < CI_; ++oo)
            s += Wo[oo] * Wv[oo * C_ + c];
        Wbf[o * C_ + c] = f2bf(s);
        if (c == 0) {
            float ts = 0.f;
            #pragma unroll 8
            for (int oo = 0; oo < CI_; ++oo) ts += Wo[oo] * bv[oo];
            bias[256] = ts;
        }
    } else {
        Wbf[o * C_ + c] = 0;
        if (c == 0) bias[o] = 0.f;
    }
}

// k1: MFMA GEMM. THIS ROUND: x tile staged to LDS as bf16 via coalesced
// float4 loads (2 per thread); each lane's B-fragment is ONE ds_read_b128
// per k-step (was 8 serialized strided scalar global loads). 8 waves/block
// split the 17 M-tiles ({2,..,2,3}). D lane map: col(px)=l&15,
// row(o)=(l>>4)*4+r (HW-verified m89; chain-verified passing).
__global__ __launch_bounds__(512) void k1_proj(
    const float* __restrict__ x, const u16* __restrict__ Wbf,
    const float* __restrict__ bias,
    u16* __restrict__ qk, float* __restrict__ vs) {
    __shared__ u16 xs[16][264];                          // [px][c], row 528 B
    const int t = threadIdx.x;
    const int l = t & 63;
    const int w = t >> 6;                                // wave 0..7
    const int lane16 = l & 15;
    const int g = l >> 4;
    const int p0 = blockIdx.x * 16;
    const int b = p0 >> 12;
    const int pin = p0 & 4095;
    const int px = p0 + lane16;                          // this lane's global pixel

    {   // stage: thread t loads 8 px of channel c = t>>1, converts to bf16
        const int c = t >> 1;
        const int ph = (t & 1) * 8;
        const float* src = x + (size_t)(b * C_ + c) * NPB_ + pin + ph;
        const float4 v0 = *reinterpret_cast<const float4*>(src);
        const float4 v1 = *reinterpret_cast<const float4*>(src + 4);
        xs[ph + 0][c] = f2bf(v0.x); xs[ph + 1][c] = f2bf(v0.y);
        xs[ph + 2][c] = f2bf(v0.z); xs[ph + 3][c] = f2bf(v0.w);
        xs[ph + 4][c] = f2bf(v1.x); xs[ph + 5][c] = f2bf(v1.y);
        xs[ph + 6][c] = f2bf(v1.z); xs[ph + 7][c] = f2bf(v1.w);
    }
    __syncthreads();

    const int mt0 = 2 * w;                               // first m-tile
    const int nmt = (w < 7) ? 2 : 3;                     // wave 7: 14,15,16

    f32x4_t acc[3];
    #pragma unroll
    for (int n = 0; n < 3; ++n) {
        const int mt = mt0 + n;
        #pragma unroll
        for (int r = 0; r < 4; ++r)
            acc[n][r] = (n < nmt) ? bias[mt * 16 + g * 4 + r] : 0.f;
    }

    #pragma unroll
    for (int kk = 0; kk < 8; ++kk) {                     // K = 256, step 32
        const int c0 = kk * 32 + g * 8;
        const bf16x8_t bv = *reinterpret_cast<const bf16x8_t*>(&xs[lane16][c0]);
        const u16* arow = Wbf + c0 + (size_t)(mt0 * 16 + lane16) * C_;
        #pragma unroll
        for (int n = 0; n < 3; ++n) {
            if (n < nmt) {
                const bf16x8_t av = *reinterpret_cast<const bf16x8_t*>(arow + (size_t)n * 16 * C_);
                acc[n] = __builtin_amdgcn_mfma_f32_16x16x32_bf16(av, bv, acc[n], 0, 0, 0);
            }
        }
    }

    // epilogue: qk rows are channel-last per pixel
    u16* qrow = qk + (size_t)px * C_;
    #pragma unroll
    for (int n = 0; n < 3; ++n) {
        const int mt = mt0 + n;
        if (n < nmt && mt < 16) {
            u32* dst = reinterpret_cast<u32*>(qrow + mt * 16 + g * 4);
            dst[0] = (u32)f2bf(acc[n][0]) | ((u32)f2bf(acc[n][1]) << 16);
            dst[1] = (u32)f2bf(acc[n][2]) | ((u32)f2bf(acc[n][3]) << 16);
        }
    }
    if (w == 7 && g == 0) vs[px] = acc[2][0];   // row 256 = vs
}

// k2: one wave per pixel. THIS ROUND: bijective XCD-contiguous blockIdx
// swizzle (4096 blocks % 8 XCDs == 0) so each XCD gathers from a contiguous
// half-image (~1.2 MB working set, fits 4 MB XCD L2; was whole-8.4MB thrash).
// lane l: tap = min(l&15, 8); branchless clamped gather, validity in weight.
// A/B share (lane,elem)->k map so HW k-permutation cancels; C/D: col=l&15,
// row=(l>>4)*4+reg (m89).
__global__ __launch_bounds__(256) void k2_attn(
    const float* __restrict__ off, const u16* __restrict__ qk,
    const float* __restrict__ vs, const float* __restrict__ bo,
    float* __restrict__ out) {
    const int t = threadIdx.x;
    const int l = t & 63;
    const int bid = blockIdx.x;
    const int swz = (bid & 7) * ((int)gridDim.x >> 3) + (bid >> 3);  // XCD-contiguous
    const int pixel = swz * 4 + (t >> 6);
    const int b = pixel >> 12;
    const int rem = pixel & 4095;
    const int y = rem >> 6, xx = rem & 63;
    const int l16 = l & 15;
    const int tap = (l16 < K_) ? l16 : (K_ - 1);
    const int g = l >> 4;

    const float* offb = off + ((size_t)b * (2 * K_) + 2 * tap) * NPB_ + rem;
    const float oy = offb[0];
    const float ox = offb[NPB_];
    const float py = (float)(y + tap / 3 - 1) + oy;
    const float px = (float)(xx + tap % 3 - 1) + ox;
    const float fy0 = floorf(py), fx0 = floorf(px);
    const float fy = py - fy0, fx = px - fx0;
    const int y0 = (int)fy0, x0 = (int)fx0;

    const u16* qkb = qk + ((size_t)(b << 12)) * C_ + g * 8;
    const float* vsm = vs + (b << 12);

    // 4 corner weights (validity-masked) + clamped base pointers
    float wgt[4];
    int ppc[4];
    const u16* bp[4];
    #pragma unroll
    for (int c = 0; c < 4; ++c) {
        const int dy = c >> 1, dx = c & 1;
        const int yi = y0 + dy, xi = x0 + dx;
        const float wv = (dy ? fy : 1.f - fy) * (dx ? fx : 1.f - fx);
        const int ok = (yi >= 0) & (yi < H_) & (xi >= 0) & (xi < W_);
        const int yc = min(max(yi, 0), H_ - 1);
        const int xc = min(max(xi, 0), W_ - 1);
        ppc[c] = yc * W_ + xc;
        wgt[c] = ok ? wv : 0.f;
        bp[c] = qkb + (size_t)ppc[c] * C_;
    }

    // issue all corner loads up front (static indices), then consume
    uint4 qv[4][4], kv[4][4];       // [corner][s-phase]
    #pragma unroll
    for (int c = 0; c < 4; ++c) {
        #pragma unroll
        for (int s = 0; s < 4; ++s) {
            qv[c][s] = *reinterpret_cast<const uint4*>(bp[c] + s * 32);
            kv[c][s] = *reinterpret_cast<const uint4*>(bp[c] + CI_ + s * 32);
        }
    }
    const float vsu_t = wgt[0] * vsm[ppc[0]] + wgt[1] * vsm[ppc[1]] +
                        wgt[2] * vsm[ppc[2]] + wgt[3] * vsm[ppc[3]];

    f32x2_t fq[16], fk[16];   // bilinear-accumulated q/k channels (f32x2 pairs)
    #pragma unroll
    for (int e = 0; e < 16; ++e) { fq[e] = (f32x2_t){0.f, 0.f}; fk[e] = (f32x2_t){0.f, 0.f}; }
    #pragma unroll
    for (int s = 0; s < 4; ++s) {
        #pragma unroll
        for (int c = 0; c < 4; ++c) {
            const f32x2_t w2 = {wgt[c], wgt[c]};
            acc8p(&fq[s * 4], qv[c][s], w2);
            acc8p(&fk[s * 4], kv[c][s], w2);
        }
    }

    // 4 MFMA steps: acc[r] = S[i = tap][j = g*4 + r]
    f32x4_t acc = {0.f, 0.f, 0.f, 0.f};
    #pragma unroll
    for (int s = 0; s < 4; ++s) {
        bf16x8_t av, bv;
        #pragma unroll
        for (int e = 0; e < 4; ++e) {
            av[2 * e]     = (__bf16)fk[s * 4 + e].x;   // A = ku (rows j)
            av[2 * e + 1] = (__bf16)fk[s * 4 + e].y;
            bv[2 * e]     = (__bf16)fq[s * 4 + e].x;   // B = qu (cols i)
            bv[2 * e + 1] = (__bf16)fq[s * 4 + e].y;
        }
        acc = __builtin_amdgcn_mfma_f32_16x16x32_bf16(av, bv, acc, 0, 0, 0);
    }

    // softmax over j for fixed i = tap; j spread across lane groups (stride-16 lanes)
    float mx = -1e30f;
    #pragma unroll
    for (int r = 0; r < 4; ++r) {
        const int j = g * 4 + r;
        if (j < K_) mx = fmaxf(mx, acc[r]);
    }
    mx = fmaxf(mx, __shfl_xor(mx, 16, 64));
    mx = fmaxf(mx, __shfl_xor(mx, 32, 64));

    float vj[4];
    #pragma unroll
    for (int r = 0; r < 4; ++r) vj[r] = __shfl(vsu_t, g * 4 + r, 64);  // vsu[j] from lane j

    float den = 0.f, num = 0.f;
    #pragma unroll
    for (int r = 0; r < 4; ++r) {
        const int j = g * 4 + r;
        if (j < K_) {
            const float e = __expf(acc[r] - mx);
            den += e;
            num += e * vj[r];
        }
    }
    den += __shfl_xor(den, 16, 64); den += __shfl_xor(den, 32, 64);
    num += __shfl_xor(num, 16, 64); num += __shfl_xor(num, 32, 64);

    if (l < K_) {
        const float z = num / den + bo[0];
        out[(size_t)b * K_ * NPB_ + (size_t)l * NPB_ + rem] = 1.f / (1.f + __expf(-z));
    }
}

extern "C" void kernel_launch(void* const* d_in, const int* in_sizes, int n_in,
                              void* d_out, int out_size, void* d_ws, size_t ws_size,
                              hipStream_t stream) {
    const float* x   = (const float*)d_in[0];
    const float* off = (const float*)d_in[1];
    const float* Wq  = (const float*)d_in[2];
    const float* bq  = (const float*)d_in[3];
    const float* Wk  = (const float*)d_in[4];
    const float* bk  = (const float*)d_in[5];
    const float* Wv  = (const float*)d_in[6];
    const float* bv  = (const float*)d_in[7];
    const float* Wo  = (const float*)d_in[8];
    const float* bo  = (const float*)d_in[9];
    float* out = (float*)d_out;

    char* ws = (char*)d_ws;
    u16*   qkbuf = (u16*)(ws + 4096);                 // 16384*256 bf16 = 8 MiB
    float* vsmap = (float*)(ws + 4096 + 8388608);     // 16384 f32 = 64 KiB
    u16*   Wbf   = (u16*)(ws + 4096 + 8388608 + 65536);        // 272*256 bf16
    float* bias  = (float*)(ws + 4096 + 8388608 + 65536 + 139264);  // 272 f32

    k0b_prep<<<MROWS_, 256, 0, stream>>>(Wq, bq, Wk, bk, Wv, bv, Wo, Wbf, bias);
    k1_proj<<<NP_ / 16, 512, 0, stream>>>(x, Wbf, bias, qkbuf, vsmap);
    k2_attn<<<NP_ / 4, 256, 0, stream>>>(off, qkbuf, vsmap, bo, out);
}

// Round 10
// 76.928 us; speedup vs baseline: 2.1283x; 1.0147x over previous
//
#include <hip/hip_runtime.h>

typedef unsigned short u16;
typedef unsigned int u32;

#define B_   4
#define C_   256
#define CI_  128
#define H_   64
#define W_   64
#define NPB_ 4096     // pixels per batch image
#define NP_  16384    // total pixels
#define K_   9        // 3x3 taps
#define MROWS_ 272    // 128 q + 128 k + 1 wcomb + 15 pad

typedef __attribute__((ext_vector_type(8))) __bf16 bf16x8_t;
typedef __attribute__((ext_vector_type(4))) float f32x4_t;
typedef __attribute__((ext_vector_type(2))) float f32x2_t;

__device__ __forceinline__ float bf2f(u16 u) {
    union { u32 i; float f; } x; x.i = ((u32)u) << 16; return x.f;
}
__device__ __forceinline__ float bf2f_lo(u32 w) {
    union { u32 i; float f; } x; x.i = w << 16; return x.f;
}
__device__ __forceinline__ float bf2f_hi(u32 w) {
    union { u32 i; float f; } x; x.i = w & 0xffff0000u; return x.f;
}
__device__ __forceinline__ u16 f2bf(float f) {  // round-to-nearest-even
    union { float f; u32 i; } x; x.f = f;
    u32 lsb = (x.i >> 16) & 1u;
    return (u16)((x.i + 0x7fffu + lsb) >> 16);
}
// packed bilinear accumulate: 8 bf16 channels, f32x2 lanes -> v_pk_fma_f32
__device__ __forceinline__ void acc8p(f32x2_t* f, uint4 v, f32x2_t w2) {
    f32x2_t p;
    p.x = bf2f_lo(v.x); p.y = bf2f_hi(v.x); f[0] += w2 * p;
    p.x = bf2f_lo(v.y); p.y = bf2f_hi(v.y); f[1] += w2 * p;
    p.x = bf2f_lo(v.z); p.y = bf2f_hi(v.z); f[2] += w2 * p;
    p.x = bf2f_lo(v.w); p.y = bf2f_hi(v.w); f[3] += w2 * p;
}

// k0b: prepare Wt in FRAGMENT-TILED layout + bias[272].
// Wt[((mt*8+kk)*64 + lane)*8 + e] = Wrow(mt*16+(lane&15))[kk*32+(lane>>4)*8+e]
// so k1's A-load per (mt,kk) is one fully-coalesced 1KB wave load.
__global__ void k0b_prep(const float* __restrict__ Wq, const float* __restrict__ bq,
                         const float* __restrict__ Wk, const float* __restrict__ bk,
                         const float* __restrict__ Wv, const float* __restrict__ bv,
                         const float* __restrict__ Wo,
                         u16* __restrict__ Wt, float* __restrict__ bias) {
    const int o = blockIdx.x;   // 0..271 (row)
    const int c = threadIdx.x;  // 0..255 (channel)
    u16 val;
    if (o < 128) {
        val = f2bf(Wq[o * C_ + c]);
        if (c == 0) bias[o] = bq[o];
    } else if (o < 256) {
        val = f2bf(Wk[(o - 128) * C_ + c]);
        if (c == 0) bias[o] = bk[o - 128];
    } else if (o == 256) {
        float s = 0.f;
        #pragma unroll 8
        for (int oo = 0; oo < CI_; ++oo)
            s += Wo[oo] * Wv[oo * C_ + c];
        val = f2bf(s);
        if (c == 0) {
            float ts = 0.f;
            #pragma unroll 8
            for (int oo = 0; oo < CI_; ++oo) ts += Wo[oo] * bv[oo];
            bias[256] = ts;
        }
    } else {
        val = 0;
        if (c == 0) bias[o] = 0.f;
    }
    const int mt = o >> 4, l16 = o & 15;
    const int kk = c >> 5, g = (c >> 3) & 3, e = c & 7;
    Wt[(size_t)((mt * 8 + kk) * 64 + g * 16 + l16) * 8 + e] = val;
}

// k1: MFMA GEMM, branch-free. 8 waves/block, wave w owns m-tiles {2w,2w+1,16}
// (tile 16 = vs row, computed redundantly, written by wave 0 only). A-loads
// are 1KB coalesced wave loads from tiled Wt; B-frags via one ds_read_b128
// from a 16x272 bf16 LDS x-tile. D map: col(px)=l&15, row=(l>>4)*4+r (m89).
__global__ __launch_bounds__(512) void k1_proj(
    const float* __restrict__ x, const u16* __restrict__ Wt,
    const float* __restrict__ bias,
    u16* __restrict__ qk, float* __restrict__ vs) {
    __shared__ u16 xs[16][272];                          // row 544 B (16B-mult)
    const int t = threadIdx.x;
    const int l = t & 63;
    const int w = t >> 6;                                // wave 0..7
    const int lane16 = l & 15;
    const int g = l >> 4;
    const int p0 = blockIdx.x * 16;
    const int b = p0 >> 12;
    const int pin = p0 & 4095;

    {   // stage: thread t -> pixel t&15, channels (t>>4)*8 .. +7
        const int spx = t & 15, cg = t >> 4;             // cg 0..31
        const float* src = x + (size_t)(b * C_ + cg * 8) * NPB_ + pin + spx;
        float v[8];
        #pragma unroll
        for (int i = 0; i < 8; ++i) v[i] = src[(size_t)i * NPB_];
        uint4 pk;
        pk.x = (u32)f2bf(v[0]) | ((u32)f2bf(v[1]) << 16);
        pk.y = (u32)f2bf(v[2]) | ((u32)f2bf(v[3]) << 16);
        pk.z = (u32)f2bf(v[4]) | ((u32)f2bf(v[5]) << 16);
        pk.w = (u32)f2bf(v[6]) | ((u32)f2bf(v[7]) << 16);
        *reinterpret_cast<uint4*>(&xs[spx][cg * 8]) = pk;
    }
    __syncthreads();

    const int mts[3] = {2 * w, 2 * w + 1, 16};
    f32x4_t acc[3];
    #pragma unroll
    for (int n = 0; n < 3; ++n)
        #pragma unroll
        for (int r = 0; r < 4; ++r)
            acc[n][r] = bias[mts[n] * 16 + g * 4 + r];

    #pragma unroll
    for (int kk = 0; kk < 8; ++kk) {                     // K = 256, step 32
        const bf16x8_t bv = *reinterpret_cast<const bf16x8_t*>(&xs[lane16][kk * 32 + g * 8]);
        #pragma unroll
        for (int n = 0; n < 3; ++n) {
            const bf16x8_t av = *reinterpret_cast<const bf16x8_t*>(
                Wt + (size_t)((mts[n] * 8 + kk) * 64 + l) * 8);
            acc[n] = __builtin_amdgcn_mfma_f32_16x16x32_bf16(av, bv, acc[n], 0, 0, 0);
        }
    }

    // epilogue
    const int px = p0 + lane16;
    u16* qrow = qk + (size_t)px * C_;
    #pragma unroll
    for (int n = 0; n < 2; ++n) {
        const int mt = mts[n];
        u32* dst = reinterpret_cast<u32*>(qrow + mt * 16 + g * 4);
        dst[0] = (u32)f2bf(acc[n][0]) | ((u32)f2bf(acc[n][1]) << 16);
        dst[1] = (u32)f2bf(acc[n][2]) | ((u32)f2bf(acc[n][3]) << 16);
    }
    if (w == 0 && g == 0) vs[px] = acc[2][0];   // row 256 = vs
}

// k2: one wave per pixel; XCD-contiguous swizzle; branchless clamped gather.
// THIS ROUND: sched_barrier(0) between load-issue and consume + launch_bounds
// (256,1) -> forces all 32 gather results live (~200 VGPR), ONE vmcnt drain
// instead of 4+ serialized latency rounds. C/D: col=l&15, row=(l>>4)*4+r.
__global__ __launch_bounds__(256, 1) void k2_attn(
    const float* __restrict__ off, const u16* __restrict__ qk,
    const float* __restrict__ vs, const float* __restrict__ bo,
    float* __restrict__ out) {
    const int t = threadIdx.x;
    const int l = t & 63;
    const int bid = blockIdx.x;
    const int swz = (bid & 7) * ((int)gridDim.x >> 3) + (bid >> 3);  // XCD-contiguous
    const int pixel = swz * 4 + (t >> 6);
    const int b = pixel >> 12;
    const int rem = pixel & 4095;
    const int y = rem >> 6, xx = rem & 63;
    const int l16 = l & 15;
    const int tap = (l16 < K_) ? l16 : (K_ - 1);
    const int g = l >> 4;

    const float* offb = off + ((size_t)b * (2 * K_) + 2 * tap) * NPB_ + rem;
    const float oy = offb[0];
    const float ox = offb[NPB_];
    const float py = (float)(y + tap / 3 - 1) + oy;
    const float px = (float)(xx + tap % 3 - 1) + ox;
    const float fy0 = floorf(py), fx0 = floorf(px);
    const float fy = py - fy0, fx = px - fx0;
    const int y0 = (int)fy0, x0 = (int)fx0;

    const u16* qkb = qk + ((size_t)(b << 12)) * C_ + g * 8;
    const float* vsm = vs + (b << 12);

    // 4 corner weights (validity-masked) + clamped base pointers
    float wgt[4];
    int ppc[4];
    const u16* bp[4];
    #pragma unroll
    for (int c = 0; c < 4; ++c) {
        const int dy = c >> 1, dx = c & 1;
        const int yi = y0 + dy, xi = x0 + dx;
        const float wv = (dy ? fy : 1.f - fy) * (dx ? fx : 1.f - fx);
        const int ok = (yi >= 0) & (yi < H_) & (xi >= 0) & (xi < W_);
        const int yc = min(max(yi, 0), H_ - 1);
        const int xc = min(max(xi, 0), W_ - 1);
        ppc[c] = yc * W_ + xc;
        wgt[c] = ok ? wv : 0.f;
        bp[c] = qkb + (size_t)ppc[c] * C_;
    }

    // ---- issue ALL loads, then hard scheduling fence ----
    uint4 qv[4][4], kv[4][4];       // [corner][s-phase]
    #pragma unroll
    for (int c = 0; c < 4; ++c) {
        #pragma unroll
        for (int s = 0; s < 4; ++s) {
            qv[c][s] = *reinterpret_cast<const uint4*>(bp[c] + s * 32);
            kv[c][s] = *reinterpret_cast<const uint4*>(bp[c] + CI_ + s * 32);
        }
    }
    float vsc[4];
    #pragma unroll
    for (int c = 0; c < 4; ++c) vsc[c] = vsm[ppc[c]];
    __builtin_amdgcn_sched_barrier(0);   // loads stay issued above this point

    const float vsu_t = wgt[0] * vsc[0] + wgt[1] * vsc[1] +
                        wgt[2] * vsc[2] + wgt[3] * vsc[3];

    f32x2_t fq[16], fk[16];   // bilinear-accumulated q/k channels (f32x2 pairs)
    #pragma unroll
    for (int e = 0; e < 16; ++e) { fq[e] = (f32x2_t){0.f, 0.f}; fk[e] = (f32x2_t){0.f, 0.f}; }
    #pragma unroll
    for (int s = 0; s < 4; ++s) {
        #pragma unroll
        for (int c = 0; c < 4; ++c) {
            const f32x2_t w2 = {wgt[c], wgt[c]};
            acc8p(&fq[s * 4], qv[c][s], w2);
            acc8p(&fk[s * 4], kv[c][s], w2);
        }
    }

    // 4 MFMA steps: acc[r] = S[i = tap][j = g*4 + r]
    f32x4_t acc = {0.f, 0.f, 0.f, 0.f};
    #pragma unroll
    for (int s = 0; s < 4; ++s) {
        bf16x8_t av, bv;
        #pragma unroll
        for (int e = 0; e < 4; ++e) {
            av[2 * e]     = (__bf16)fk[s * 4 + e].x;   // A = ku (rows j)
            av[2 * e + 1] = (__bf16)fk[s * 4 + e].y;
            bv[2 * e]     = (__bf16)fq[s * 4 + e].x;   // B = qu (cols i)
            bv[2 * e + 1] = (__bf16)fq[s * 4 + e].y;
        }
        acc = __builtin_amdgcn_mfma_f32_16x16x32_bf16(av, bv, acc, 0, 0, 0);
    }

    // softmax over j for fixed i = tap; j spread across lane groups (stride-16 lanes)
    float mx = -1e30f;
    #pragma unroll
    for (int r = 0; r < 4; ++r) {
        const int j = g * 4 + r;
        if (j < K_) mx = fmaxf(mx, acc[r]);
    }
    mx = fmaxf(mx, __shfl_xor(mx, 16, 64));
    mx = fmaxf(mx, __shfl_xor(mx, 32, 64));

    float vj[4];
    #pragma unroll
    for (int r = 0; r < 4; ++r) vj[r] = __shfl(vsu_t, g * 4 + r, 64);  // vsu[j] from lane j

    float den = 0.f, num = 0.f;
    #pragma unroll
    for (int r = 0; r < 4; ++r) {
        const int j = g * 4 + r;
        if (j < K_) {
            const float e = __expf(acc[r] - mx);
            den += e;
            num += e * vj[r];
        }
    }
    den += __shfl_xor(den, 16, 64); den += __shfl_xor(den, 32, 64);
    num += __shfl_xor(num, 16, 64); num += __shfl_xor(num, 32, 64);

    if (l < K_) {
        const float z = num / den + bo[0];
        out[(size_t)b * K_ * NPB_ + (size_t)l * NPB_ + rem] = 1.f / (1.f + __expf(-z));
    }
}

extern "C" void kernel_launch(void* const* d_in, const int* in_sizes, int n_in,
                              void* d_out, int out_size, void* d_ws, size_t ws_size,
                              hipStream_t stream) {
    const float* x   = (const float*)d_in[0];
    const float* off = (const float*)d_in[1];
    const float* Wq  = (const float*)d_in[2];
    const float* bq  = (const float*)d_in[3];
    const float* Wk  = (const float*)d_in[4];
    const float* bk  = (const float*)d_in[5];
    const float* Wv  = (const float*)d_in[6];
    const float* bv  = (const float*)d_in[7];
    const float* Wo  = (const float*)d_in[8];
    const float* bo  = (const float*)d_in[9];
    float* out = (float*)d_out;

    char* ws = (char*)d_ws;
    u16*   qkbuf = (u16*)(ws + 4096);                 // 16384*256 bf16 = 8 MiB
    float* vsmap = (float*)(ws + 4096 + 8388608);     // 16384 f32 = 64 KiB
    u16*   Wt    = (u16*)(ws + 4096 + 8388608 + 65536);        // 272*256 bf16 tiled
    float* bias  = (float*)(ws + 4096 + 8388608 + 65536 + 139264);  // 272 f32

    k0b_prep<<<MROWS_, 256, 0, stream>>>(Wq, bq, Wk, bk, Wv, bv, Wo, Wt, bias);
    k1_proj<<<NP_ / 16, 512, 0, stream>>>(x, Wt, bias, qkbuf, vsmap);
    k2_attn<<<NP_ / 4, 256, 0, stream>>>(off, qkbuf, vsmap, bo, out);
}